// Round 18
// baseline (263.760 us; speedup 1.0000x reference)
//
#include <hip/hip_runtime.h>

#define NA 100000
#define NB 100000
#define ND 50000
#define HDIM 128
#define DOUT 16
// concatenated dst-node space: rel0 d:[0,ND) rel1 d:[ND,2ND) rel2 a:[2ND,2ND+NA) rel3 b:[2ND+NA,...)
#define NODE_TOT (2*ND + NA + NB)
#define BSH 9
#define BKN 512
#define NBUCKET ((NODE_TOT + BKN - 1) >> BSH)   // 586
#define BCAP 8192                                // fixed pairs capacity per bucket
#define EPB 4096                                 // edges per block, bucket passes
#define TP 136                                   // LDS tile pitch in shorts (272B, 16B-aligned)

typedef __attribute__((ext_vector_type(8))) short short8v;   // 8 bf16 (4 VGPRs)
typedef __attribute__((ext_vector_type(4))) float f32x4;

__device__ __forceinline__ unsigned short f2bf(float f) {
    unsigned u = __float_as_uint(f);
    return (unsigned short)((u + 0x7fffu + ((u >> 16) & 1u)) >> 16);
}
__device__ __forceinline__ void addbf2(float& x, float& y, unsigned u) {
    x += __uint_as_float(u << 16);
    y += __uint_as_float(u & 0xffff0000u);
}

// gather one 128-ch bf16 row-mean: 16 lanes (q = lane&15), 8 loads in flight (hand-ILP;
// VGPR=32 round-17 build had MLP~3 — this forces 8 named uint4 regs per batch).
__device__ __forceinline__ void gather_row(const unsigned int* __restrict__ tbl,
                                           const int* __restrict__ csr,
                                           int s0, int deg, int q,
                                           float& a0, float& a1, float& a2, float& a3,
                                           float& a4, float& a5, float& a6, float& a7) {
    for (int j = 0; j < deg; j += 16) {
        int cnt = deg - j; if (cnt > 16) cnt = 16;
        int myidx = (j + q < deg) ? csr[s0 + j + q] : 0;
        uint4 v[8];
        #pragma unroll
        for (int k = 0; k < 8; ++k)
            if (k < cnt) v[k] = *(const uint4*)(tbl + (size_t)__shfl(myidx, k, 16)*64 + q*4);
        #pragma unroll
        for (int k = 0; k < 8; ++k)
            if (k < cnt) { addbf2(a0,a1,v[k].x); addbf2(a2,a3,v[k].y);
                           addbf2(a4,a5,v[k].z); addbf2(a6,a7,v[k].w); }
        #pragma unroll
        for (int k = 8; k < 16; ++k)
            if (k < cnt) v[k-8] = *(const uint4*)(tbl + (size_t)__shfl(myidx, k, 16)*64 + q*4);
        #pragma unroll
        for (int k = 8; k < 16; ++k)
            if (k < cnt) { addbf2(a0,a1,v[k-8].x); addbf2(a2,a3,v[k-8].y);
                           addbf2(a4,a5,v[k-8].z); addbf2(a6,a7,v[k-8].w); }
    }
}

struct EdgeT { int node; int src; };
__device__ __forceinline__ EdgeT edge_at(int g,
    const int* __restrict__ s0, const int* __restrict__ d0,
    const int* __restrict__ s1, const int* __restrict__ d1,
    const int* __restrict__ s2, const int* __restrict__ d2,
    const int* __restrict__ s3, const int* __restrict__ d3,
    int E0, int E1, int E2) {
    EdgeT e;
    if (g < E0)             { e.node = d0[g];                    e.src = s0[g]; }
    else if (g < E0+E1)     { e.node = ND + d1[g-E0];            e.src = s1[g-E0]; }
    else if (g < E0+E1+E2)  { e.node = 2*ND + d2[g-E0-E1];       e.src = s2[g-E0-E1]; }
    else                    { e.node = 2*ND+NA + d3[g-E0-E1-E2]; e.src = s3[g-E0-E1-E2]; }
    return e;
}

// ---------------- weights (f32, for the 128->16 path) ----------------
__global__ __launch_bounds__(256) void k_weights(const float* __restrict__ basis,
                                                 const float* __restrict__ coef,
                                                 float* __restrict__ W0, float* __restrict__ W1,
                                                 int r0, int r1, int n) {
    int i = blockIdx.x * 256 + threadIdx.x;
    if (i >= n) return;
    float b0 = basis[i], b1 = basis[n + i];
    W0[i] = coef[r0*2+0]*b0 + coef[r0*2+1]*b1;
    W1[i] = coef[r1*2+0]*b0 + coef[r1*2+1]*b1;
}

// bf16 TRANSPOSED weights for MFMA B-operand: WT[n][k] = W[k][n], 128x128
__global__ __launch_bounds__(256) void k_weights_bfT(const float* __restrict__ basis,
                                                     const float* __restrict__ coef,
                                                     unsigned short* __restrict__ WT0,
                                                     unsigned short* __restrict__ WT1,
                                                     int r0, int r1) {
    int i = blockIdx.x * 256 + threadIdx.x;   // i = k*128 + j
    if (i >= HDIM*HDIM) return;
    int k = i >> 7, j = i & 127;
    float b0 = basis[i], b1 = basis[HDIM*HDIM + i];
    WT0[(size_t)j*HDIM + k] = f2bf(coef[r0*2+0]*b0 + coef[r0*2+1]*b1);
    WT1[(size_t)j*HDIM + k] = f2bf(coef[r1*2+0]*b0 + coef[r1*2+1]*b1);
}

// ---------------- fp32 -> bf16 conversion, a and b merged ----------------
__global__ __launch_bounds__(256) void k_cvt_bf16_ab(const float* __restrict__ ina,
                                                     const float* __restrict__ inb,
                                                     unsigned int* __restrict__ outa,
                                                     unsigned int* __restrict__ outb) {
    int i = blockIdx.x * 256 + threadIdx.x;    // grid exact: (NA+NB)*16
    const float* in; unsigned int* out;
    if (i < NA*16) { in = ina; out = outa; }
    else           { in = inb; out = outb; i -= NA*16; }
    const float4 a = *(const float4*)(in + (size_t)i*8);
    const float4 b = *(const float4*)(in + (size_t)i*8 + 4);
    uint4 p;
    p.x = (unsigned)f2bf(a.x) | ((unsigned)f2bf(a.y) << 16);
    p.y = (unsigned)f2bf(a.z) | ((unsigned)f2bf(a.w) << 16);
    p.z = (unsigned)f2bf(b.x) | ((unsigned)f2bf(b.y) << 16);
    p.w = (unsigned)f2bf(b.z) | ((unsigned)f2bf(b.w) << 16);
    *(uint4*)(out + (size_t)i*4) = p;
}

// ---------------- bucketed CSR build (fixed-capacity buckets) ----------------
__global__ __launch_bounds__(256) void k_ginit(int* __restrict__ gcur) {
    int i = blockIdx.x * 256 + threadIdx.x;
    if (i < NBUCKET) gcur[i] = i * BCAP;
}

__global__ __launch_bounds__(256) void k_bscatter(const int* __restrict__ s0, const int* __restrict__ d0,
                                                  const int* __restrict__ s1, const int* __restrict__ d1,
                                                  const int* __restrict__ s2, const int* __restrict__ d2,
                                                  const int* __restrict__ s3, const int* __restrict__ d3,
                                                  int E0, int E1, int E2, int Etot,
                                                  int* __restrict__ gcur,
                                                  unsigned int* __restrict__ pairs) {
    __shared__ int hist[NBUCKET];
    __shared__ int base[NBUCKET];
    for (int i = threadIdx.x; i < NBUCKET; i += 256) hist[i] = 0;
    __syncthreads();
    int g0 = blockIdx.x * EPB + threadIdx.x;
    int nd[EPB/256], sr[EPB/256], rk[EPB/256];
    #pragma unroll
    for (int i = 0; i < EPB/256; ++i) {
        int g = g0 + i*256;
        if (g < Etot) {
            EdgeT e = edge_at(g, s0,d0,s1,d1,s2,d2,s3,d3, E0,E1,E2);
            nd[i] = e.node; sr[i] = e.src;
            rk[i] = atomicAdd(&hist[e.node >> BSH], 1);
        } else nd[i] = -1;
    }
    __syncthreads();
    for (int i = threadIdx.x; i < NBUCKET; i += 256)
        if (hist[i]) base[i] = atomicAdd(&gcur[i], hist[i]);
    __syncthreads();
    #pragma unroll
    for (int i = 0; i < EPB/256; ++i) {
        if (nd[i] >= 0) {
            unsigned p = ((unsigned)(nd[i] & (BKN-1)) << 17) | (unsigned)sr[i];
            pairs[base[nd[i] >> BSH] + rk[i]] = p;
        }
    }
}

__global__ __launch_bounds__(256) void k_bdeg(const unsigned int* __restrict__ pairs,
                                              const int* __restrict__ gcur,
                                              int* __restrict__ deg) {
    __shared__ int ld[BKN];
    int b = blockIdx.x;
    for (int i = threadIdx.x; i < BKN; i += 256) ld[i] = 0;
    __syncthreads();
    int j0 = b * BCAP, j1 = gcur[b];
    for (int j = j0 + threadIdx.x; j < j1; j += 256)
        atomicAdd(&ld[pairs[j] >> 17], 1);
    __syncthreads();
    int nbase = b << BSH;
    for (int i = threadIdx.x; i < BKN && nbase + i < NODE_TOT; i += 256)
        deg[nbase + i] = ld[i];
}

__global__ __launch_bounds__(256) void k_bfill(const unsigned int* __restrict__ pairs,
                                               const int* __restrict__ gcur,
                                               const int* __restrict__ offs,
                                               int* __restrict__ csr) {
    __shared__ int cur[BKN];
    int b = blockIdx.x;
    int nbase = b << BSH;
    for (int i = threadIdx.x; i < BKN && nbase + i < NODE_TOT; i += 256)
        cur[i] = offs[nbase + i];
    __syncthreads();
    int j0 = b * BCAP, j1 = gcur[b];
    for (int j = j0 + threadIdx.x; j < j1; j += 256) {
        unsigned e = pairs[j];
        int p = atomicAdd(&cur[e >> 17], 1);
        csr[p] = (int)(e & 0x1FFFFu);
    }
}

// ---------------- global scans over NODE_TOT (deg -> offs) ----------------
__global__ __launch_bounds__(1024) void k_scan1(const int* __restrict__ deg,
                                                int* __restrict__ offs,
                                                int* __restrict__ bsum, int N) {
    __shared__ int sh[1024];
    int i = blockIdx.x * 1024 + threadIdx.x;
    int v = (i < N) ? deg[i] : 0;
    sh[threadIdx.x] = v;
    __syncthreads();
    for (int off = 1; off < 1024; off <<= 1) {
        int t = (threadIdx.x >= off) ? sh[threadIdx.x - off] : 0;
        __syncthreads();
        sh[threadIdx.x] += t;
        __syncthreads();
    }
    if (i < N) offs[i + 1] = sh[threadIdx.x];
    if (threadIdx.x == 1023) bsum[blockIdx.x] = sh[1023];
    if (i == 0) offs[0] = 0;
}

__global__ __launch_bounds__(1024) void k_scan2(int* __restrict__ bsum, int nb) {
    __shared__ int sh[1024];
    int t = threadIdx.x;
    sh[t] = (t < nb) ? bsum[t] : 0;
    __syncthreads();
    for (int off = 1; off < 1024; off <<= 1) {
        int v = (t >= off) ? sh[t - off] : 0;
        __syncthreads();
        sh[t] += v;
        __syncthreads();
    }
    if (t < nb) bsum[t] = sh[t];
}

__global__ __launch_bounds__(1024) void k_scan3(int* __restrict__ offs,
                                                const int* __restrict__ bsum, int N) {
    int i = blockIdx.x * 1024 + threadIdx.x;
    if (blockIdx.x > 0 && i < N) offs[i + 1] += bsum[blockIdx.x - 1];
}

// ---------------- FUSED layer-0 + layer-1, 16 rows/block, two tiles ----------------
// Both gathers run back-to-back (max loads in flight), then barrier, MFMA both tiles,
// barrier, h0=relu(acc+bias)->tA, barrier, t2=tA@WT12 / t3=tA@WT13. 3125 blocks.
__global__ __launch_bounds__(256) void k_gfused_l01(const unsigned int* __restrict__ fa,
                                                    const unsigned int* __restrict__ fb,
                                                    const int* __restrict__ offs,
                                                    const int* __restrict__ csr,
                                                    const unsigned short* __restrict__ WT0,
                                                    const unsigned short* __restrict__ WT1,
                                                    const unsigned short* __restrict__ WT12,
                                                    const unsigned short* __restrict__ WT13,
                                                    const float* __restrict__ bias,
                                                    unsigned short* __restrict__ t2out,
                                                    unsigned short* __restrict__ t3out,
                                                    int nrows) {
    __shared__ unsigned short tA[16 * TP];   // 4.35KB
    __shared__ unsigned short tB[16 * TP];
    const int t = threadIdx.x;
    const int row0 = blockIdx.x * 16;
    const int l = t & 63, wid = t >> 6;
    const int colw = wid * 32;             // this wave's 32 output cols
    const int rl = l & 15, kq = l >> 4, kl = kq * 8;
    const int q = t & 15, gslot = t >> 4;  // gather: row gslot (0..15), channel chunk q

    // ---- gather a-rows -> tA, b-rows -> tB, back to back (no barrier between) ----
    #pragma unroll
    for (int h = 0; h < 2; ++h) {
        const unsigned int* tbl = h ? fb : fa;
        unsigned short* tile = h ? tB : tA;
        const int row = row0 + gslot;
        float a0=0,a1=0,a2=0,a3=0,a4=0,a5=0,a6=0,a7=0;
        int deg = 0;
        if (row < nrows) {
            int node = (h ? ND : 0) + row;
            int s0 = offs[node];
            deg = offs[node + 1] - s0;
            gather_row(tbl, csr, s0, deg, q, a0,a1,a2,a3,a4,a5,a6,a7);
        }
        float sc = 1.0f / fmaxf((float)deg, 1.0f);
        uint4 o;
        o.x = (unsigned)f2bf(a0*sc) | ((unsigned)f2bf(a1*sc) << 16);
        o.y = (unsigned)f2bf(a2*sc) | ((unsigned)f2bf(a3*sc) << 16);
        o.z = (unsigned)f2bf(a4*sc) | ((unsigned)f2bf(a5*sc) << 16);
        o.w = (unsigned)f2bf(a6*sc) | ((unsigned)f2bf(a7*sc) << 16);
        *(uint4*)(tile + gslot*TP + q*8) = o;
    }
    __syncthreads();

    // ---- MFMA: acc[cf] += tA@WT0 + tB@WT1 (K=256 total), wave owns 32 cols ----
    f32x4 acc[2];
    acc[0] = (f32x4)0.f; acc[1] = (f32x4)0.f;
    #pragma unroll
    for (int h = 0; h < 2; ++h) {
        const unsigned short* tile = h ? tB : tA;
        const unsigned short* WT = h ? WT1 : WT0;
        #pragma unroll
        for (int s = 0; s < 4; ++s) {
            const int k0 = s * 32;
            short8v a = *(const short8v*)(tile + rl*TP + k0 + kl);
            #pragma unroll
            for (int cf = 0; cf < 2; ++cf) {
                short8v b = *(const short8v*)(WT + (size_t)(colw + cf*16 + rl)*HDIM + k0 + kl);
                acc[cf] = __builtin_amdgcn_mfma_f32_16x16x32_bf16(a, b, acc[cf], 0, 0, 0);
            }
        }
    }
    __syncthreads();   // all MFMA reads of tA done before h0 overwrite

    // ---- h0 = relu(acc + bias) -> tA (bf16); D row = kq*4+j (0..15), col = colw+cf*16+rl ----
    #pragma unroll
    for (int cf = 0; cf < 2; ++cf) {
        const float bc = bias[colw + cf*16 + rl];
        #pragma unroll
        for (int j = 0; j < 4; ++j)
            tA[(kq*4 + j)*TP + colw + cf*16 + rl] = f2bf(fmaxf(acc[cf][j] + bc, 0.f));
    }
    __syncthreads();

    // ---- layer-1 transforms: t2 = h0@WT12, t3 = h0@WT13 ----
    #pragma unroll
    for (int h2 = 0; h2 < 2; ++h2) {
        const unsigned short* WT = h2 ? WT13 : WT12;
        unsigned short* outp = h2 ? t3out : t2out;
        f32x4 a2[2];
        a2[0] = (f32x4)0.f; a2[1] = (f32x4)0.f;
        #pragma unroll
        for (int s = 0; s < 4; ++s) {
            const int k0 = s * 32;
            short8v a = *(const short8v*)(tA + rl*TP + k0 + kl);
            #pragma unroll
            for (int cf = 0; cf < 2; ++cf) {
                short8v b = *(const short8v*)(WT + (size_t)(colw + cf*16 + rl)*HDIM + k0 + kl);
                a2[cf] = __builtin_amdgcn_mfma_f32_16x16x32_bf16(a, b, a2[cf], 0, 0, 0);
            }
        }
        #pragma unroll
        for (int cf = 0; cf < 2; ++cf)
            #pragma unroll
            for (int j = 0; j < 4; ++j) {
                int row = row0 + kq*4 + j;
                if (row < nrows)
                    outp[(size_t)row*HDIM + colw + cf*16 + rl] = f2bf(a2[cf][j]);
            }
    }
}

// ---------------- merged fused gather + bias/relu + 128->16 transform (a and b) ----------------
// NA%16==0 so each 16-row block is purely a-side or purely b-side: stage one W, transposed.
__global__ __launch_bounds__(256) void k_gather_trans16_ab(const unsigned int* __restrict__ t2,
                                                           const unsigned int* __restrict__ t3,
                                                           const int* __restrict__ offs,   // offs_all
                                                           const int* __restrict__ csr,
                                                           const float* __restrict__ bias,
                                                           const float* __restrict__ W20,
                                                           const float* __restrict__ W21,
                                                           float* __restrict__ t1a,
                                                           float* __restrict__ t1b) {
    __shared__ float WlT[16 * 132];       // WlT[j][c] = W[c][j]
    __shared__ float vbuf[16 * 132];
    const int t = threadIdx.x;
    const bool blkA = (blockIdx.x < NA/16);
    const float* W = blkA ? W20 : W21;
    {
        const int jj = t & 15, c0 = (t >> 4) * 8;
        #pragma unroll
        for (int i = 0; i < 8; ++i)
            WlT[jj*132 + c0 + i] = W[(size_t)(c0 + i)*DOUT + jj];
    }
    __syncthreads();
    const int w = t >> 6, l = t & 63;
    const int sub = l >> 4, q = l & 15;
    const int lrow = w * 4 + sub;
    const int node = 2*ND + blockIdx.x * 16 + lrow;    // grid exact: < NODE_TOT
    const unsigned int* tbl = blkA ? t2 : t3;
    const int s0 = offs[node];
    const int deg = offs[node + 1] - s0;
    float a0=0,a1=0,a2=0,a3=0,a4=0,a5=0,a6=0,a7=0;
    gather_row(tbl, csr, s0, deg, q, a0,a1,a2,a3,a4,a5,a6,a7);
    const float sc = 1.0f / fmaxf((float)deg, 1.0f);
    const float4 bi0 = *(const float4*)(bias + q*8);
    const float4 bi1 = *(const float4*)(bias + q*8 + 4);
    float4 v0, v1;
    v0.x = fmaxf(a0*sc + bi0.x, 0.f); v0.y = fmaxf(a1*sc + bi0.y, 0.f);
    v0.z = fmaxf(a2*sc + bi0.z, 0.f); v0.w = fmaxf(a3*sc + bi0.w, 0.f);
    v1.x = fmaxf(a4*sc + bi1.x, 0.f); v1.y = fmaxf(a5*sc + bi1.y, 0.f);
    v1.z = fmaxf(a6*sc + bi1.z, 0.f); v1.w = fmaxf(a7*sc + bi1.w, 0.f);
    *(float4*)(vbuf + lrow*132 + q*8)     = v0;
    *(float4*)(vbuf + lrow*132 + q*8 + 4) = v1;
    __syncthreads();
    const int rr = t >> 4, jj = t & 15;
    const float* vr = vbuf + rr*132;
    const float* wr = WlT + jj*132;
    float4 acc4 = make_float4(0.f, 0.f, 0.f, 0.f);
    #pragma unroll 8
    for (int c4 = 0; c4 < 32; ++c4) {
        const float4 v = *(const float4*)(vr + c4*4);
        const float4 ww = *(const float4*)(wr + c4*4);
        acc4.x += v.x*ww.x; acc4.y += v.y*ww.y; acc4.z += v.z*ww.z; acc4.w += v.w*ww.w;
    }
    float acc = (acc4.x + acc4.y) + (acc4.z + acc4.w);
    const int grow = blockIdx.x * 16 + rr;
    if (blkA) t1a[(size_t)grow*DOUT + jj] = acc;
    else      t1b[(size_t)(grow - NA)*DOUT + jj] = acc;
}

// final: out[d] = mean-gather(t0 via rel0) + mean-gather(t1 via rel1) + bias
__global__ __launch_bounds__(256) void k_gather16_combine(const float* __restrict__ t0,
                                                          const float* __restrict__ t1,
                                                          const int* __restrict__ offs0,
                                                          const int* __restrict__ offs1,
                                                          const int* __restrict__ csr,
                                                          const float* __restrict__ bias,
                                                          float* __restrict__ out, int nrows) {
    int t = threadIdx.x;
    int row = blockIdx.x * 64 + (t >> 2);
    if (row >= nrows) return;
    int q = t & 3;
    int c = q * 4;
    float4 acc = make_float4(0.f, 0.f, 0.f, 0.f);
    {
        int s0 = offs0[row], deg = offs0[row + 1] - s0;
        for (int j = 0; j < deg; j += 4) {
            int cnt = deg - j; if (cnt > 4) cnt = 4;
            int myidx = (j + q < deg) ? csr[s0 + j + q] : 0;
            #pragma unroll
            for (int k = 0; k < 4; ++k) {
                if (k < cnt) {
                    int s = __shfl(myidx, k, 4);
                    float4 v = *reinterpret_cast<const float4*>(t0 + (size_t)s*DOUT + c);
                    acc.x += v.x; acc.y += v.y; acc.z += v.z; acc.w += v.w;
                }
            }
        }
        float sc = 1.0f / fmaxf((float)deg, 1.0f);
        acc.x *= sc; acc.y *= sc; acc.z *= sc; acc.w *= sc;
    }
    float4 acc2 = make_float4(0.f, 0.f, 0.f, 0.f);
    {
        int u0 = offs1[row], deg = offs1[row + 1] - u0;
        for (int j = 0; j < deg; j += 4) {
            int cnt = deg - j; if (cnt > 4) cnt = 4;
            int myidx = (j + q < deg) ? csr[u0 + j + q] : 0;
            #pragma unroll
            for (int k = 0; k < 4; ++k) {
                if (k < cnt) {
                    int s = __shfl(myidx, k, 4);
                    float4 v = *reinterpret_cast<const float4*>(t1 + (size_t)s*DOUT + c);
                    acc2.x += v.x; acc2.y += v.y; acc2.z += v.z; acc2.w += v.w;
                }
            }
        }
        float sc2 = 1.0f / fmaxf((float)deg, 1.0f);
        acc2.x *= sc2; acc2.y *= sc2; acc2.z *= sc2; acc2.w *= sc2;
    }
    float4 bi = *reinterpret_cast<const float4*>(bias + c);
    acc.x += acc2.x + bi.x; acc.y += acc2.y + bi.y;
    acc.z += acc2.z + bi.z; acc.w += acc2.w + bi.w;
    *reinterpret_cast<float4*>(out + (size_t)row*DOUT + c) = acc;
}

extern "C" void kernel_launch(void* const* d_in, const int* in_sizes, int n_in,
                              void* d_out, int out_size, void* d_ws, size_t ws_size,
                              hipStream_t stream) {
    const float* feat_a = (const float*)d_in[0];
    const float* feat_b = (const float*)d_in[1];
    const float* basis0 = (const float*)d_in[3];
    const float* coef0  = (const float*)d_in[4];
    const float* bias0  = (const float*)d_in[5];
    const float* basis1 = (const float*)d_in[6];
    const float* coef1  = (const float*)d_in[7];
    const float* bias1  = (const float*)d_in[8];
    const float* basis2 = (const float*)d_in[9];
    const float* coef2  = (const float*)d_in[10];
    const float* bias2  = (const float*)d_in[11];
    const int* s0 = (const int*)d_in[12]; const int* d0 = (const int*)d_in[13];
    const int* s1 = (const int*)d_in[14]; const int* d1 = (const int*)d_in[15];
    const int* s2 = (const int*)d_in[16]; const int* d2 = (const int*)d_in[17];
    const int* s3 = (const int*)d_in[18]; const int* d3 = (const int*)d_in[19];
    const int E0 = in_sizes[12], E1 = in_sizes[14], E2 = in_sizes[16], E3 = in_sizes[18];
    const int Etot = E0 + E1 + E2 + E3;

    // ---- workspace carve-up ----
    char* base = (char*)d_ws;
    auto alloc = [&](size_t bytes) { char* p = base; base += (bytes + 255) & ~(size_t)255; return p; };
    unsigned short* WT00 = (unsigned short*)alloc(HDIM*HDIM*2);
    unsigned short* WT01 = (unsigned short*)alloc(HDIM*HDIM*2);
    unsigned short* WT12 = (unsigned short*)alloc(HDIM*HDIM*2);
    unsigned short* WT13 = (unsigned short*)alloc(HDIM*HDIM*2);
    float* W20 = (float*)alloc(HDIM*DOUT*4);
    float* W21 = (float*)alloc(HDIM*DOUT*4);
    int* offs_all = (int*)alloc((NODE_TOT + 1) * 4);
    int* csr_all  = (int*)alloc((size_t)Etot * 4);
    int* bsum     = (int*)alloc(2048 * 4);
    int* deg      = (int*)alloc(NODE_TOT * 4);
    int* gcur     = (int*)alloc(NBUCKET * 4);
    unsigned int* pairs = (unsigned int*)alloc((size_t)NBUCKET * BCAP * 4);  // 19.2MB fixed regions
    unsigned int* fa_bf  = (unsigned int*)alloc((size_t)NA*HDIM*2);
    unsigned int* fb_bf  = (unsigned int*)alloc((size_t)NB*HDIM*2);
    unsigned int* t2_bf  = (unsigned int*)alloc((size_t)ND*HDIM*2);
    unsigned int* t3_bf  = (unsigned int*)alloc((size_t)ND*HDIM*2);
    float* t1a  = (float*)alloc((size_t)NA*DOUT*4);
    float* t1b  = (float*)alloc((size_t)NB*DOUT*4);
    float* out = (float*)d_out;

    const int* offsR[2] = {offs_all, offs_all + ND};
    const int nbE = (Etot + EPB - 1) / EPB;

    // ---- 1. relation weights + feat bf16 conversion ----
    k_weights_bfT<<<(HDIM*HDIM+255)/256, 256, 0, stream>>>(basis0, coef0, WT00, WT01, 0, 1);
    k_weights_bfT<<<(HDIM*HDIM+255)/256, 256, 0, stream>>>(basis1, coef1, WT12, WT13, 2, 3);
    k_weights<<<(HDIM*DOUT+255)/256, 256, 0, stream>>>(basis2, coef2, W20, W21, 0, 1, HDIM*DOUT);
    k_cvt_bf16_ab<<<((NA+NB)*16)/256, 256, 0, stream>>>(feat_a, feat_b, fa_bf, fb_bf);

    // ---- 2. bucketed CSR build (fixed-capacity buckets) ----
    {
        k_ginit<<<(NBUCKET+255)/256, 256, 0, stream>>>(gcur);
        k_bscatter<<<nbE, 256, 0, stream>>>(s0,d0,s1,d1,s2,d2,s3,d3, E0,E1,E2, Etot, gcur, pairs);
        k_bdeg<<<NBUCKET, 256, 0, stream>>>(pairs, gcur, deg);
        int nb = (NODE_TOT + 1023) / 1024;
        k_scan1<<<nb, 1024, 0, stream>>>(deg, offs_all, bsum, NODE_TOT);
        k_scan2<<<1, 1024, 0, stream>>>(bsum, nb);
        k_scan3<<<nb, 1024, 0, stream>>>(offs_all, bsum, NODE_TOT);
        k_bfill<<<NBUCKET, 256, 0, stream>>>(pairs, gcur, offs_all, csr_all);
    }

    // ---- 3. fused layers 0+1: gather a+b -> MFMA -> h0 (LDS-only) -> t2,t3 (bf16) ----
    k_gfused_l01<<<(ND+15)/16, 256, 0, stream>>>(fa_bf, fb_bf, offs_all, csr_all,
                                                 WT00, WT01, WT12, WT13, bias0,
                                                 (unsigned short*)t2_bf, (unsigned short*)t3_bf, ND);

    // ---- 4. fused layer-1 aggregate + bias/relu + layer-2 transform ----
    k_gather_trans16_ab<<<(NA+NB)/16, 256, 0, stream>>>(t2_bf, t3_bf, offs_all, csr_all,
                                                        bias1, W20, W21, t1a, t1b);

    // ---- 5. final combine ----
    k_gather16_combine<<<(ND+63)/64, 256, 0, stream>>>(t1a, t1b, offsR[0], offsR[1], csr_all,
                                                       bias2, out, ND);
}

// Round 19
// 241.779 us; speedup vs baseline: 1.0909x; 1.0909x over previous
//
#include <hip/hip_runtime.h>

#define NA 100000
#define NB 100000
#define ND 50000
#define HDIM 128
#define DOUT 16
// concatenated dst-node space: rel0 d:[0,ND) rel1 d:[ND,2ND) rel2 a:[2ND,2ND+NA) rel3 b:[2ND+NA,...)
#define NODE_TOT (2*ND + NA + NB)
#define BSH 9
#define BKN 512
#define NBUCKET ((NODE_TOT + BKN - 1) >> BSH)   // 586
#define BCAP 8192                                // fixed pairs capacity per bucket
#define EPB 4096                                 // edges per block, bucket passes
#define TP 136                                   // LDS tile pitch in shorts (272B, 16B-aligned)

typedef __attribute__((ext_vector_type(8))) short short8v;   // 8 bf16 (4 VGPRs)
typedef __attribute__((ext_vector_type(4))) float f32x4;

__device__ __forceinline__ unsigned short f2bf(float f) {
    unsigned u = __float_as_uint(f);
    return (unsigned short)((u + 0x7fffu + ((u >> 16) & 1u)) >> 16);
}
__device__ __forceinline__ void addbf2(float& x, float& y, unsigned u) {
    x += __uint_as_float(u << 16);
    y += __uint_as_float(u & 0xffff0000u);
}

// gather one 128-ch bf16 row-mean: 16 lanes (q = lane&15).
// Loads are UNCONDITIONAL (OOB lanes carry myidx=0 -> safe row-0 read, same line)
// so the compiler can batch 8 global_load_dwordx4 before the first waitcnt;
// only the accumulates are predicated (VALU, no control flow). Round-18 fix:
// round-17's per-load `if` serialized the loads (VGPR stayed 36, MLP~3).
__device__ __forceinline__ void gather_row(const unsigned int* __restrict__ tbl,
                                           const int* __restrict__ csr,
                                           int s0, int deg, int q,
                                           float& a0, float& a1, float& a2, float& a3,
                                           float& a4, float& a5, float& a6, float& a7) {
    for (int j = 0; j < deg; j += 16) {
        int cnt = deg - j; if (cnt > 16) cnt = 16;
        int myidx = (j + q < deg) ? csr[s0 + j + q] : 0;
        uint4 v[8];
        #pragma unroll
        for (int k = 0; k < 8; ++k)
            v[k] = *(const uint4*)(tbl + (size_t)__shfl(myidx, k, 16)*64 + q*4);
        #pragma unroll
        for (int k = 0; k < 8; ++k)
            if (k < cnt) { addbf2(a0,a1,v[k].x); addbf2(a2,a3,v[k].y);
                           addbf2(a4,a5,v[k].z); addbf2(a6,a7,v[k].w); }
        if (cnt > 8) {
            #pragma unroll
            for (int k = 8; k < 16; ++k)
                v[k-8] = *(const uint4*)(tbl + (size_t)__shfl(myidx, k, 16)*64 + q*4);
            #pragma unroll
            for (int k = 8; k < 16; ++k)
                if (k < cnt) { addbf2(a0,a1,v[k-8].x); addbf2(a2,a3,v[k-8].y);
                               addbf2(a4,a5,v[k-8].z); addbf2(a6,a7,v[k-8].w); }
        }
    }
}

struct EdgeT { int node; int src; };
__device__ __forceinline__ EdgeT edge_at(int g,
    const int* __restrict__ s0, const int* __restrict__ d0,
    const int* __restrict__ s1, const int* __restrict__ d1,
    const int* __restrict__ s2, const int* __restrict__ d2,
    const int* __restrict__ s3, const int* __restrict__ d3,
    int E0, int E1, int E2) {
    EdgeT e;
    if (g < E0)             { e.node = d0[g];                    e.src = s0[g]; }
    else if (g < E0+E1)     { e.node = ND + d1[g-E0];            e.src = s1[g-E0]; }
    else if (g < E0+E1+E2)  { e.node = 2*ND + d2[g-E0-E1];       e.src = s2[g-E0-E1]; }
    else                    { e.node = 2*ND+NA + d3[g-E0-E1-E2]; e.src = s3[g-E0-E1-E2]; }
    return e;
}

// ---------------- weights (f32, for the 128->16 path) ----------------
__global__ __launch_bounds__(256) void k_weights(const float* __restrict__ basis,
                                                 const float* __restrict__ coef,
                                                 float* __restrict__ W0, float* __restrict__ W1,
                                                 int r0, int r1, int n) {
    int i = blockIdx.x * 256 + threadIdx.x;
    if (i >= n) return;
    float b0 = basis[i], b1 = basis[n + i];
    W0[i] = coef[r0*2+0]*b0 + coef[r0*2+1]*b1;
    W1[i] = coef[r1*2+0]*b0 + coef[r1*2+1]*b1;
}

// bf16 TRANSPOSED weights for MFMA B-operand: WT[n][k] = W[k][n], 128x128
__global__ __launch_bounds__(256) void k_weights_bfT(const float* __restrict__ basis,
                                                     const float* __restrict__ coef,
                                                     unsigned short* __restrict__ WT0,
                                                     unsigned short* __restrict__ WT1,
                                                     int r0, int r1) {
    int i = blockIdx.x * 256 + threadIdx.x;   // i = k*128 + j
    if (i >= HDIM*HDIM) return;
    int k = i >> 7, j = i & 127;
    float b0 = basis[i], b1 = basis[HDIM*HDIM + i];
    WT0[(size_t)j*HDIM + k] = f2bf(coef[r0*2+0]*b0 + coef[r0*2+1]*b1);
    WT1[(size_t)j*HDIM + k] = f2bf(coef[r1*2+0]*b0 + coef[r1*2+1]*b1);
}

// ---------------- fp32 -> bf16 conversion, a and b merged ----------------
__global__ __launch_bounds__(256) void k_cvt_bf16_ab(const float* __restrict__ ina,
                                                     const float* __restrict__ inb,
                                                     unsigned int* __restrict__ outa,
                                                     unsigned int* __restrict__ outb) {
    int i = blockIdx.x * 256 + threadIdx.x;    // grid exact: (NA+NB)*16
    const float* in; unsigned int* out;
    if (i < NA*16) { in = ina; out = outa; }
    else           { in = inb; out = outb; i -= NA*16; }
    const float4 a = *(const float4*)(in + (size_t)i*8);
    const float4 b = *(const float4*)(in + (size_t)i*8 + 4);
    uint4 p;
    p.x = (unsigned)f2bf(a.x) | ((unsigned)f2bf(a.y) << 16);
    p.y = (unsigned)f2bf(a.z) | ((unsigned)f2bf(a.w) << 16);
    p.z = (unsigned)f2bf(b.x) | ((unsigned)f2bf(b.y) << 16);
    p.w = (unsigned)f2bf(b.z) | ((unsigned)f2bf(b.w) << 16);
    *(uint4*)(out + (size_t)i*4) = p;
}

// ---------------- bucketed CSR build (fixed-capacity buckets) ----------------
__global__ __launch_bounds__(256) void k_ginit(int* __restrict__ gcur) {
    int i = blockIdx.x * 256 + threadIdx.x;
    if (i < NBUCKET) gcur[i] = i * BCAP;
}

__global__ __launch_bounds__(256) void k_bscatter(const int* __restrict__ s0, const int* __restrict__ d0,
                                                  const int* __restrict__ s1, const int* __restrict__ d1,
                                                  const int* __restrict__ s2, const int* __restrict__ d2,
                                                  const int* __restrict__ s3, const int* __restrict__ d3,
                                                  int E0, int E1, int E2, int Etot,
                                                  int* __restrict__ gcur,
                                                  unsigned int* __restrict__ pairs) {
    __shared__ int hist[NBUCKET];
    __shared__ int base[NBUCKET];
    for (int i = threadIdx.x; i < NBUCKET; i += 256) hist[i] = 0;
    __syncthreads();
    int g0 = blockIdx.x * EPB + threadIdx.x;
    int nd[EPB/256], sr[EPB/256], rk[EPB/256];
    #pragma unroll
    for (int i = 0; i < EPB/256; ++i) {
        int g = g0 + i*256;
        if (g < Etot) {
            EdgeT e = edge_at(g, s0,d0,s1,d1,s2,d2,s3,d3, E0,E1,E2);
            nd[i] = e.node; sr[i] = e.src;
            rk[i] = atomicAdd(&hist[e.node >> BSH], 1);
        } else nd[i] = -1;
    }
    __syncthreads();
    for (int i = threadIdx.x; i < NBUCKET; i += 256)
        if (hist[i]) base[i] = atomicAdd(&gcur[i], hist[i]);
    __syncthreads();
    #pragma unroll
    for (int i = 0; i < EPB/256; ++i) {
        if (nd[i] >= 0) {
            unsigned p = ((unsigned)(nd[i] & (BKN-1)) << 17) | (unsigned)sr[i];
            pairs[base[nd[i] >> BSH] + rk[i]] = p;
        }
    }
}

__global__ __launch_bounds__(256) void k_bdeg(const unsigned int* __restrict__ pairs,
                                              const int* __restrict__ gcur,
                                              int* __restrict__ deg) {
    __shared__ int ld[BKN];
    int b = blockIdx.x;
    for (int i = threadIdx.x; i < BKN; i += 256) ld[i] = 0;
    __syncthreads();
    int j0 = b * BCAP, j1 = gcur[b];
    for (int j = j0 + threadIdx.x; j < j1; j += 256)
        atomicAdd(&ld[pairs[j] >> 17], 1);
    __syncthreads();
    int nbase = b << BSH;
    for (int i = threadIdx.x; i < BKN && nbase + i < NODE_TOT; i += 256)
        deg[nbase + i] = ld[i];
}

__global__ __launch_bounds__(256) void k_bfill(const unsigned int* __restrict__ pairs,
                                               const int* __restrict__ gcur,
                                               const int* __restrict__ offs,
                                               int* __restrict__ csr) {
    __shared__ int cur[BKN];
    int b = blockIdx.x;
    int nbase = b << BSH;
    for (int i = threadIdx.x; i < BKN && nbase + i < NODE_TOT; i += 256)
        cur[i] = offs[nbase + i];
    __syncthreads();
    int j0 = b * BCAP, j1 = gcur[b];
    for (int j = j0 + threadIdx.x; j < j1; j += 256) {
        unsigned e = pairs[j];
        int p = atomicAdd(&cur[e >> 17], 1);
        csr[p] = (int)(e & 0x1FFFFu);
    }
}

// ---------------- global scans over NODE_TOT (deg -> offs) ----------------
__global__ __launch_bounds__(1024) void k_scan1(const int* __restrict__ deg,
                                                int* __restrict__ offs,
                                                int* __restrict__ bsum, int N) {
    __shared__ int sh[1024];
    int i = blockIdx.x * 1024 + threadIdx.x;
    int v = (i < N) ? deg[i] : 0;
    sh[threadIdx.x] = v;
    __syncthreads();
    for (int off = 1; off < 1024; off <<= 1) {
        int t = (threadIdx.x >= off) ? sh[threadIdx.x - off] : 0;
        __syncthreads();
        sh[threadIdx.x] += t;
        __syncthreads();
    }
    if (i < N) offs[i + 1] = sh[threadIdx.x];
    if (threadIdx.x == 1023) bsum[blockIdx.x] = sh[1023];
    if (i == 0) offs[0] = 0;
}

__global__ __launch_bounds__(1024) void k_scan2(int* __restrict__ bsum, int nb) {
    __shared__ int sh[1024];
    int t = threadIdx.x;
    sh[t] = (t < nb) ? bsum[t] : 0;
    __syncthreads();
    for (int off = 1; off < 1024; off <<= 1) {
        int v = (t >= off) ? sh[t - off] : 0;
        __syncthreads();
        sh[t] += v;
        __syncthreads();
    }
    if (t < nb) bsum[t] = sh[t];
}

__global__ __launch_bounds__(1024) void k_scan3(int* __restrict__ offs,
                                                const int* __restrict__ bsum, int N) {
    int i = blockIdx.x * 1024 + threadIdx.x;
    if (blockIdx.x > 0 && i < N) offs[i + 1] += bsum[blockIdx.x - 1];
}

// ---------------- FUSED layer-0 + layer-1, 16 rows/block, two tiles ----------------
__global__ __launch_bounds__(256) void k_gfused_l01(const unsigned int* __restrict__ fa,
                                                    const unsigned int* __restrict__ fb,
                                                    const int* __restrict__ offs,
                                                    const int* __restrict__ csr,
                                                    const unsigned short* __restrict__ WT0,
                                                    const unsigned short* __restrict__ WT1,
                                                    const unsigned short* __restrict__ WT12,
                                                    const unsigned short* __restrict__ WT13,
                                                    const float* __restrict__ bias,
                                                    unsigned short* __restrict__ t2out,
                                                    unsigned short* __restrict__ t3out,
                                                    int nrows) {
    __shared__ unsigned short tA[16 * TP];   // 4.35KB
    __shared__ unsigned short tB[16 * TP];
    const int t = threadIdx.x;
    const int row0 = blockIdx.x * 16;
    const int l = t & 63, wid = t >> 6;
    const int colw = wid * 32;             // this wave's 32 output cols
    const int rl = l & 15, kq = l >> 4, kl = kq * 8;
    const int q = t & 15, gslot = t >> 4;  // gather: row gslot (0..15), channel chunk q

    // ---- gather a-rows -> tA, b-rows -> tB, back to back (no barrier between) ----
    #pragma unroll
    for (int h = 0; h < 2; ++h) {
        const unsigned int* tbl = h ? fb : fa;
        unsigned short* tile = h ? tB : tA;
        const int row = row0 + gslot;
        float a0=0,a1=0,a2=0,a3=0,a4=0,a5=0,a6=0,a7=0;
        int deg = 0;
        if (row < nrows) {
            int node = (h ? ND : 0) + row;
            int s0 = offs[node];
            deg = offs[node + 1] - s0;
            gather_row(tbl, csr, s0, deg, q, a0,a1,a2,a3,a4,a5,a6,a7);
        }
        float sc = 1.0f / fmaxf((float)deg, 1.0f);
        uint4 o;
        o.x = (unsigned)f2bf(a0*sc) | ((unsigned)f2bf(a1*sc) << 16);
        o.y = (unsigned)f2bf(a2*sc) | ((unsigned)f2bf(a3*sc) << 16);
        o.z = (unsigned)f2bf(a4*sc) | ((unsigned)f2bf(a5*sc) << 16);
        o.w = (unsigned)f2bf(a6*sc) | ((unsigned)f2bf(a7*sc) << 16);
        *(uint4*)(tile + gslot*TP + q*8) = o;
    }
    __syncthreads();

    // ---- MFMA: acc[cf] += tA@WT0 + tB@WT1 (K=256 total), wave owns 32 cols ----
    f32x4 acc[2];
    acc[0] = (f32x4)0.f; acc[1] = (f32x4)0.f;
    #pragma unroll
    for (int h = 0; h < 2; ++h) {
        const unsigned short* tile = h ? tB : tA;
        const unsigned short* WT = h ? WT1 : WT0;
        #pragma unroll
        for (int s = 0; s < 4; ++s) {
            const int k0 = s * 32;
            short8v a = *(const short8v*)(tile + rl*TP + k0 + kl);
            #pragma unroll
            for (int cf = 0; cf < 2; ++cf) {
                short8v b = *(const short8v*)(WT + (size_t)(colw + cf*16 + rl)*HDIM + k0 + kl);
                acc[cf] = __builtin_amdgcn_mfma_f32_16x16x32_bf16(a, b, acc[cf], 0, 0, 0);
            }
        }
    }
    __syncthreads();   // all MFMA reads of tA done before h0 overwrite

    // ---- h0 = relu(acc + bias) -> tA (bf16); D row = kq*4+j (0..15), col = colw+cf*16+rl ----
    #pragma unroll
    for (int cf = 0; cf < 2; ++cf) {
        const float bc = bias[colw + cf*16 + rl];
        #pragma unroll
        for (int j = 0; j < 4; ++j)
            tA[(kq*4 + j)*TP + colw + cf*16 + rl] = f2bf(fmaxf(acc[cf][j] + bc, 0.f));
    }
    __syncthreads();

    // ---- layer-1 transforms: t2 = h0@WT12, t3 = h0@WT13 ----
    #pragma unroll
    for (int h2 = 0; h2 < 2; ++h2) {
        const unsigned short* WT = h2 ? WT13 : WT12;
        unsigned short* outp = h2 ? t3out : t2out;
        f32x4 a2[2];
        a2[0] = (f32x4)0.f; a2[1] = (f32x4)0.f;
        #pragma unroll
        for (int s = 0; s < 4; ++s) {
            const int k0 = s * 32;
            short8v a = *(const short8v*)(tA + rl*TP + k0 + kl);
            #pragma unroll
            for (int cf = 0; cf < 2; ++cf) {
                short8v b = *(const short8v*)(WT + (size_t)(colw + cf*16 + rl)*HDIM + k0 + kl);
                a2[cf] = __builtin_amdgcn_mfma_f32_16x16x32_bf16(a, b, a2[cf], 0, 0, 0);
            }
        }
        #pragma unroll
        for (int cf = 0; cf < 2; ++cf)
            #pragma unroll
            for (int j = 0; j < 4; ++j) {
                int row = row0 + kq*4 + j;
                if (row < nrows)
                    outp[(size_t)row*HDIM + colw + cf*16 + rl] = f2bf(a2[cf][j]);
            }
    }
}

// ---------------- merged fused gather + bias/relu + 128->16 transform (a and b) ----------------
// NA%16==0 so each 16-row block is purely a-side or purely b-side: stage one W, transposed.
__global__ __launch_bounds__(256) void k_gather_trans16_ab(const unsigned int* __restrict__ t2,
                                                           const unsigned int* __restrict__ t3,
                                                           const int* __restrict__ offs,   // offs_all
                                                           const int* __restrict__ csr,
                                                           const float* __restrict__ bias,
                                                           const float* __restrict__ W20,
                                                           const float* __restrict__ W21,
                                                           float* __restrict__ t1a,
                                                           float* __restrict__ t1b) {
    __shared__ float WlT[16 * 132];       // WlT[j][c] = W[c][j]
    __shared__ float vbuf[16 * 132];
    const int t = threadIdx.x;
    const bool blkA = (blockIdx.x < NA/16);
    const float* W = blkA ? W20 : W21;
    {
        const int jj = t & 15, c0 = (t >> 4) * 8;
        #pragma unroll
        for (int i = 0; i < 8; ++i)
            WlT[jj*132 + c0 + i] = W[(size_t)(c0 + i)*DOUT + jj];
    }
    __syncthreads();
    const int w = t >> 6, l = t & 63;
    const int sub = l >> 4, q = l & 15;
    const int lrow = w * 4 + sub;
    const int node = 2*ND + blockIdx.x * 16 + lrow;    // grid exact: < NODE_TOT
    const unsigned int* tbl = blkA ? t2 : t3;
    const int s0 = offs[node];
    const int deg = offs[node + 1] - s0;
    float a0=0,a1=0,a2=0,a3=0,a4=0,a5=0,a6=0,a7=0;
    gather_row(tbl, csr, s0, deg, q, a0,a1,a2,a3,a4,a5,a6,a7);
    const float sc = 1.0f / fmaxf((float)deg, 1.0f);
    const float4 bi0 = *(const float4*)(bias + q*8);
    const float4 bi1 = *(const float4*)(bias + q*8 + 4);
    float4 v0, v1;
    v0.x = fmaxf(a0*sc + bi0.x, 0.f); v0.y = fmaxf(a1*sc + bi0.y, 0.f);
    v0.z = fmaxf(a2*sc + bi0.z, 0.f); v0.w = fmaxf(a3*sc + bi0.w, 0.f);
    v1.x = fmaxf(a4*sc + bi1.x, 0.f); v1.y = fmaxf(a5*sc + bi1.y, 0.f);
    v1.z = fmaxf(a6*sc + bi1.z, 0.f); v1.w = fmaxf(a7*sc + bi1.w, 0.f);
    *(float4*)(vbuf + lrow*132 + q*8)     = v0;
    *(float4*)(vbuf + lrow*132 + q*8 + 4) = v1;
    __syncthreads();
    const int rr = t >> 4, jj = t & 15;
    const float* vr = vbuf + rr*132;
    const float* wr = WlT + jj*132;
    float4 acc4 = make_float4(0.f, 0.f, 0.f, 0.f);
    #pragma unroll 8
    for (int c4 = 0; c4 < 32; ++c4) {
        const float4 v = *(const float4*)(vr + c4*4);
        const float4 ww = *(const float4*)(wr + c4*4);
        acc4.x += v.x*ww.x; acc4.y += v.y*ww.y; acc4.z += v.z*ww.z; acc4.w += v.w*ww.w;
    }
    float acc = (acc4.x + acc4.y) + (acc4.z + acc4.w);
    const int grow = blockIdx.x * 16 + rr;
    if (blkA) t1a[(size_t)grow*DOUT + jj] = acc;
    else      t1b[(size_t)(grow - NA)*DOUT + jj] = acc;
}

// final: out[d] = mean-gather(t0 via rel0) + mean-gather(t1 via rel1) + bias
__global__ __launch_bounds__(256) void k_gather16_combine(const float* __restrict__ t0,
                                                          const float* __restrict__ t1,
                                                          const int* __restrict__ offs0,
                                                          const int* __restrict__ offs1,
                                                          const int* __restrict__ csr,
                                                          const float* __restrict__ bias,
                                                          float* __restrict__ out, int nrows) {
    int t = threadIdx.x;
    int row = blockIdx.x * 64 + (t >> 2);
    if (row >= nrows) return;
    int q = t & 3;
    int c = q * 4;
    float4 acc = make_float4(0.f, 0.f, 0.f, 0.f);
    {
        int s0 = offs0[row], deg = offs0[row + 1] - s0;
        for (int j = 0; j < deg; j += 4) {
            int cnt = deg - j; if (cnt > 4) cnt = 4;
            int myidx = (j + q < deg) ? csr[s0 + j + q] : 0;
            float4 v[4];
            #pragma unroll
            for (int k = 0; k < 4; ++k)
                v[k] = *reinterpret_cast<const float4*>(t0 + (size_t)__shfl(myidx, k, 4)*DOUT + c);
            #pragma unroll
            for (int k = 0; k < 4; ++k)
                if (k < cnt) { acc.x += v[k].x; acc.y += v[k].y; acc.z += v[k].z; acc.w += v[k].w; }
        }
        float sc = 1.0f / fmaxf((float)deg, 1.0f);
        acc.x *= sc; acc.y *= sc; acc.z *= sc; acc.w *= sc;
    }
    float4 acc2 = make_float4(0.f, 0.f, 0.f, 0.f);
    {
        int u0 = offs1[row], deg = offs1[row + 1] - u0;
        for (int j = 0; j < deg; j += 4) {
            int cnt = deg - j; if (cnt > 4) cnt = 4;
            int myidx = (j + q < deg) ? csr[u0 + j + q] : 0;
            float4 v[4];
            #pragma unroll
            for (int k = 0; k < 4; ++k)
                v[k] = *reinterpret_cast<const float4*>(t1 + (size_t)__shfl(myidx, k, 4)*DOUT + c);
            #pragma unroll
            for (int k = 0; k < 4; ++k)
                if (k < cnt) { acc2.x += v[k].x; acc2.y += v[k].y; acc2.z += v[k].z; acc2.w += v[k].w; }
        }
        float sc2 = 1.0f / fmaxf((float)deg, 1.0f);
        acc2.x *= sc2; acc2.y *= sc2; acc2.z *= sc2; acc2.w *= sc2;
    }
    float4 bi = *reinterpret_cast<const float4*>(bias + c);
    acc.x += acc2.x + bi.x; acc.y += acc2.y + bi.y;
    acc.z += acc2.z + bi.z; acc.w += acc2.w + bi.w;
    *reinterpret_cast<float4*>(out + (size_t)row*DOUT + c) = acc;
}

extern "C" void kernel_launch(void* const* d_in, const int* in_sizes, int n_in,
                              void* d_out, int out_size, void* d_ws, size_t ws_size,
                              hipStream_t stream) {
    const float* feat_a = (const float*)d_in[0];
    const float* feat_b = (const float*)d_in[1];
    const float* basis0 = (const float*)d_in[3];
    const float* coef0  = (const float*)d_in[4];
    const float* bias0  = (const float*)d_in[5];
    const float* basis1 = (const float*)d_in[6];
    const float* coef1  = (const float*)d_in[7];
    const float* bias1  = (const float*)d_in[8];
    const float* basis2 = (const float*)d_in[9];
    const float* coef2  = (const float*)d_in[10];
    const float* bias2  = (const float*)d_in[11];
    const int* s0 = (const int*)d_in[12]; const int* d0 = (const int*)d_in[13];
    const int* s1 = (const int*)d_in[14]; const int* d1 = (const int*)d_in[15];
    const int* s2 = (const int*)d_in[16]; const int* d2 = (const int*)d_in[17];
    const int* s3 = (const int*)d_in[18]; const int* d3 = (const int*)d_in[19];
    const int E0 = in_sizes[12], E1 = in_sizes[14], E2 = in_sizes[16], E3 = in_sizes[18];
    const int Etot = E0 + E1 + E2 + E3;

    // ---- workspace carve-up ----
    char* base = (char*)d_ws;
    auto alloc = [&](size_t bytes) { char* p = base; base += (bytes + 255) & ~(size_t)255; return p; };
    unsigned short* WT00 = (unsigned short*)alloc(HDIM*HDIM*2);
    unsigned short* WT01 = (unsigned short*)alloc(HDIM*HDIM*2);
    unsigned short* WT12 = (unsigned short*)alloc(HDIM*HDIM*2);
    unsigned short* WT13 = (unsigned short*)alloc(HDIM*HDIM*2);
    float* W20 = (float*)alloc(HDIM*DOUT*4);
    float* W21 = (float*)alloc(HDIM*DOUT*4);
    int* offs_all = (int*)alloc((NODE_TOT + 1) * 4);
    int* csr_all  = (int*)alloc((size_t)Etot * 4);
    int* bsum     = (int*)alloc(2048 * 4);
    int* deg      = (int*)alloc(NODE_TOT * 4);
    int* gcur     = (int*)alloc(NBUCKET * 4);
    unsigned int* pairs = (unsigned int*)alloc((size_t)NBUCKET * BCAP * 4);  // 19.2MB fixed regions
    unsigned int* fa_bf  = (unsigned int*)alloc((size_t)NA*HDIM*2);
    unsigned int* fb_bf  = (unsigned int*)alloc((size_t)NB*HDIM*2);
    unsigned int* t2_bf  = (unsigned int*)alloc((size_t)ND*HDIM*2);
    unsigned int* t3_bf  = (unsigned int*)alloc((size_t)ND*HDIM*2);
    float* t1a  = (float*)alloc((size_t)NA*DOUT*4);
    float* t1b  = (float*)alloc((size_t)NB*DOUT*4);
    float* out = (float*)d_out;

    const int* offsR[2] = {offs_all, offs_all + ND};
    const int nbE = (Etot + EPB - 1) / EPB;

    // ---- 1. relation weights + feat bf16 conversion ----
    k_weights_bfT<<<(HDIM*HDIM+255)/256, 256, 0, stream>>>(basis0, coef0, WT00, WT01, 0, 1);
    k_weights_bfT<<<(HDIM*HDIM+255)/256, 256, 0, stream>>>(basis1, coef1, WT12, WT13, 2, 3);
    k_weights<<<(HDIM*DOUT+255)/256, 256, 0, stream>>>(basis2, coef2, W20, W21, 0, 1, HDIM*DOUT);
    k_cvt_bf16_ab<<<((NA+NB)*16)/256, 256, 0, stream>>>(feat_a, feat_b, fa_bf, fb_bf);

    // ---- 2. bucketed CSR build (fixed-capacity buckets) ----
    {
        k_ginit<<<(NBUCKET+255)/256, 256, 0, stream>>>(gcur);
        k_bscatter<<<nbE, 256, 0, stream>>>(s0,d0,s1,d1,s2,d2,s3,d3, E0,E1,E2, Etot, gcur, pairs);
        k_bdeg<<<NBUCKET, 256, 0, stream>>>(pairs, gcur, deg);
        int nb = (NODE_TOT + 1023) / 1024;
        k_scan1<<<nb, 1024, 0, stream>>>(deg, offs_all, bsum, NODE_TOT);
        k_scan2<<<1, 1024, 0, stream>>>(bsum, nb);
        k_scan3<<<nb, 1024, 0, stream>>>(offs_all, bsum, NODE_TOT);
        k_bfill<<<NBUCKET, 256, 0, stream>>>(pairs, gcur, offs_all, csr_all);
    }

    // ---- 3. fused layers 0+1: gather a+b -> MFMA -> h0 (LDS-only) -> t2,t3 (bf16) ----
    k_gfused_l01<<<(ND+15)/16, 256, 0, stream>>>(fa_bf, fb_bf, offs_all, csr_all,
                                                 WT00, WT01, WT12, WT13, bias0,
                                                 (unsigned short*)t2_bf, (unsigned short*)t3_bf, ND);

    // ---- 4. fused layer-1 aggregate + bias/relu + layer-2 transform ----
    k_gather_trans16_ab<<<(NA+NB)/16, 256, 0, stream>>>(t2_bf, t3_bf, offs_all, csr_all,
                                                        bias1, W20, W21, t1a, t1b);

    // ---- 5. final combine ----
    k_gather16_combine<<<(ND+63)/64, 256, 0, stream>>>(t1a, t1b, offsR[0], offsR[1], csr_all,
                                                       bias2, out, ND);
}

// Round 20
// 241.166 us; speedup vs baseline: 1.0937x; 1.0025x over previous
//
#include <hip/hip_runtime.h>

#define NA 100000
#define NB 100000
#define ND 50000
#define HDIM 128
#define DOUT 16
// concatenated dst-node space: rel0 d:[0,ND) rel1 d:[ND,2ND) rel2 a:[2ND,2ND+NA) rel3 b:[2ND+NA,...)
#define NODE_TOT (2*ND + NA + NB)
#define BSH 9
#define BKN 512
#define NBUCKET ((NODE_TOT + BKN - 1) >> BSH)   // 586
#define BCAP 8192                                // fixed pairs capacity per bucket
#define EPB 4096                                 // edges per block, bucket passes
#define TP 136                                   // LDS tile pitch in shorts (272B, 16B-aligned)

typedef __attribute__((ext_vector_type(8))) short short8v;   // 8 bf16 (4 VGPRs)
typedef __attribute__((ext_vector_type(4))) float f32x4;

__device__ __forceinline__ unsigned short f2bf(float f) {
    unsigned u = __float_as_uint(f);
    return (unsigned short)((u + 0x7fffu + ((u >> 16) & 1u)) >> 16);
}
__device__ __forceinline__ void addbf2(float& x, float& y, unsigned u) {
    x += __uint_as_float(u << 16);
    y += __uint_as_float(u & 0xffff0000u);
}

// gather one 128-ch bf16 row-mean: 16 lanes (q = lane&15).
// Loads are UNCONDITIONAL (OOB lanes carry myidx=0 -> safe row-0 read); accumulates
// predicated. Round-19 fix: VGPR=44 showed the compiler re-interleaved load/add
// pairs (MLP~4) — sched_group_barrier(VMEM_READ,8) pins each 8-load batch to issue
// before its adds. csr index for the next batch prefetched at iteration end.
__device__ __forceinline__ void gather_row(const unsigned int* __restrict__ tbl,
                                           const int* __restrict__ csr,
                                           int s0, int deg, int q,
                                           float& a0, float& a1, float& a2, float& a3,
                                           float& a4, float& a5, float& a6, float& a7) {
    int myidx = (q < deg) ? csr[s0 + q] : 0;
    for (int j = 0; j < deg; j += 16) {
        int cnt = deg - j; if (cnt > 16) cnt = 16;
        uint4 v[8];
        #pragma unroll
        for (int k = 0; k < 8; ++k)
            v[k] = *(const uint4*)(tbl + (size_t)__shfl(myidx, k, 16)*64 + q*4);
        __builtin_amdgcn_sched_group_barrier(0x020, 8, 0);   // 8 VMEM reads first
        #pragma unroll
        for (int k = 0; k < 8; ++k)
            if (k < cnt) { addbf2(a0,a1,v[k].x); addbf2(a2,a3,v[k].y);
                           addbf2(a4,a5,v[k].z); addbf2(a6,a7,v[k].w); }
        if (cnt > 8) {
            #pragma unroll
            for (int k = 8; k < 16; ++k)
                v[k-8] = *(const uint4*)(tbl + (size_t)__shfl(myidx, k, 16)*64 + q*4);
            __builtin_amdgcn_sched_group_barrier(0x020, 8, 0);
            #pragma unroll
            for (int k = 8; k < 16; ++k)
                if (k < cnt) { addbf2(a0,a1,v[k-8].x); addbf2(a2,a3,v[k-8].y);
                               addbf2(a4,a5,v[k-8].z); addbf2(a6,a7,v[k-8].w); }
        }
        myidx = (j + 16 + q < deg) ? csr[s0 + j + 16 + q] : 0;   // prefetch next batch
    }
}

struct EdgeT { int node; int src; };
__device__ __forceinline__ EdgeT edge_at(int g,
    const int* __restrict__ s0, const int* __restrict__ d0,
    const int* __restrict__ s1, const int* __restrict__ d1,
    const int* __restrict__ s2, const int* __restrict__ d2,
    const int* __restrict__ s3, const int* __restrict__ d3,
    int E0, int E1, int E2) {
    EdgeT e;
    if (g < E0)             { e.node = d0[g];                    e.src = s0[g]; }
    else if (g < E0+E1)     { e.node = ND + d1[g-E0];            e.src = s1[g-E0]; }
    else if (g < E0+E1+E2)  { e.node = 2*ND + d2[g-E0-E1];       e.src = s2[g-E0-E1]; }
    else                    { e.node = 2*ND+NA + d3[g-E0-E1-E2]; e.src = s3[g-E0-E1-E2]; }
    return e;
}

// ---------------- weights (f32, for the 128->16 path) ----------------
__global__ __launch_bounds__(256) void k_weights(const float* __restrict__ basis,
                                                 const float* __restrict__ coef,
                                                 float* __restrict__ W0, float* __restrict__ W1,
                                                 int r0, int r1, int n) {
    int i = blockIdx.x * 256 + threadIdx.x;
    if (i >= n) return;
    float b0 = basis[i], b1 = basis[n + i];
    W0[i] = coef[r0*2+0]*b0 + coef[r0*2+1]*b1;
    W1[i] = coef[r1*2+0]*b0 + coef[r1*2+1]*b1;
}

// bf16 TRANSPOSED weights for MFMA B-operand: WT[n][k] = W[k][n], 128x128
__global__ __launch_bounds__(256) void k_weights_bfT(const float* __restrict__ basis,
                                                     const float* __restrict__ coef,
                                                     unsigned short* __restrict__ WT0,
                                                     unsigned short* __restrict__ WT1,
                                                     int r0, int r1) {
    int i = blockIdx.x * 256 + threadIdx.x;   // i = k*128 + j
    if (i >= HDIM*HDIM) return;
    int k = i >> 7, j = i & 127;
    float b0 = basis[i], b1 = basis[HDIM*HDIM + i];
    WT0[(size_t)j*HDIM + k] = f2bf(coef[r0*2+0]*b0 + coef[r0*2+1]*b1);
    WT1[(size_t)j*HDIM + k] = f2bf(coef[r1*2+0]*b0 + coef[r1*2+1]*b1);
}

// ---------------- fp32 -> bf16 conversion, a and b merged ----------------
__global__ __launch_bounds__(256) void k_cvt_bf16_ab(const float* __restrict__ ina,
                                                     const float* __restrict__ inb,
                                                     unsigned int* __restrict__ outa,
                                                     unsigned int* __restrict__ outb) {
    int i = blockIdx.x * 256 + threadIdx.x;    // grid exact: (NA+NB)*16
    const float* in; unsigned int* out;
    if (i < NA*16) { in = ina; out = outa; }
    else           { in = inb; out = outb; i -= NA*16; }
    const float4 a = *(const float4*)(in + (size_t)i*8);
    const float4 b = *(const float4*)(in + (size_t)i*8 + 4);
    uint4 p;
    p.x = (unsigned)f2bf(a.x) | ((unsigned)f2bf(a.y) << 16);
    p.y = (unsigned)f2bf(a.z) | ((unsigned)f2bf(a.w) << 16);
    p.z = (unsigned)f2bf(b.x) | ((unsigned)f2bf(b.y) << 16);
    p.w = (unsigned)f2bf(b.z) | ((unsigned)f2bf(b.w) << 16);
    *(uint4*)(out + (size_t)i*4) = p;
}

// ---------------- bucketed CSR build (fixed-capacity buckets) ----------------
__global__ __launch_bounds__(256) void k_ginit(int* __restrict__ gcur) {
    int i = blockIdx.x * 256 + threadIdx.x;
    if (i < NBUCKET) gcur[i] = i * BCAP;
}

__global__ __launch_bounds__(256) void k_bscatter(const int* __restrict__ s0, const int* __restrict__ d0,
                                                  const int* __restrict__ s1, const int* __restrict__ d1,
                                                  const int* __restrict__ s2, const int* __restrict__ d2,
                                                  const int* __restrict__ s3, const int* __restrict__ d3,
                                                  int E0, int E1, int E2, int Etot,
                                                  int* __restrict__ gcur,
                                                  unsigned int* __restrict__ pairs) {
    __shared__ int hist[NBUCKET];
    __shared__ int base[NBUCKET];
    for (int i = threadIdx.x; i < NBUCKET; i += 256) hist[i] = 0;
    __syncthreads();
    int g0 = blockIdx.x * EPB + threadIdx.x;
    int nd[EPB/256], sr[EPB/256], rk[EPB/256];
    #pragma unroll
    for (int i = 0; i < EPB/256; ++i) {
        int g = g0 + i*256;
        if (g < Etot) {
            EdgeT e = edge_at(g, s0,d0,s1,d1,s2,d2,s3,d3, E0,E1,E2);
            nd[i] = e.node; sr[i] = e.src;
            rk[i] = atomicAdd(&hist[e.node >> BSH], 1);
        } else nd[i] = -1;
    }
    __syncthreads();
    for (int i = threadIdx.x; i < NBUCKET; i += 256)
        if (hist[i]) base[i] = atomicAdd(&gcur[i], hist[i]);
    __syncthreads();
    #pragma unroll
    for (int i = 0; i < EPB/256; ++i) {
        if (nd[i] >= 0) {
            unsigned p = ((unsigned)(nd[i] & (BKN-1)) << 17) | (unsigned)sr[i];
            pairs[base[nd[i] >> BSH] + rk[i]] = p;
        }
    }
}

__global__ __launch_bounds__(256) void k_bdeg(const unsigned int* __restrict__ pairs,
                                              const int* __restrict__ gcur,
                                              int* __restrict__ deg) {
    __shared__ int ld[BKN];
    int b = blockIdx.x;
    for (int i = threadIdx.x; i < BKN; i += 256) ld[i] = 0;
    __syncthreads();
    int j0 = b * BCAP, j1 = gcur[b];
    for (int j = j0 + threadIdx.x; j < j1; j += 256)
        atomicAdd(&ld[pairs[j] >> 17], 1);
    __syncthreads();
    int nbase = b << BSH;
    for (int i = threadIdx.x; i < BKN && nbase + i < NODE_TOT; i += 256)
        deg[nbase + i] = ld[i];
}

__global__ __launch_bounds__(256) void k_bfill(const unsigned int* __restrict__ pairs,
                                               const int* __restrict__ gcur,
                                               const int* __restrict__ offs,
                                               int* __restrict__ csr) {
    __shared__ int cur[BKN];
    int b = blockIdx.x;
    int nbase = b << BSH;
    for (int i = threadIdx.x; i < BKN && nbase + i < NODE_TOT; i += 256)
        cur[i] = offs[nbase + i];
    __syncthreads();
    int j0 = b * BCAP, j1 = gcur[b];
    for (int j = j0 + threadIdx.x; j < j1; j += 256) {
        unsigned e = pairs[j];
        int p = atomicAdd(&cur[e >> 17], 1);
        csr[p] = (int)(e & 0x1FFFFu);
    }
}

// ---------------- global scans over NODE_TOT (deg -> offs) ----------------
__global__ __launch_bounds__(1024) void k_scan1(const int* __restrict__ deg,
                                                int* __restrict__ offs,
                                                int* __restrict__ bsum, int N) {
    __shared__ int sh[1024];
    int i = blockIdx.x * 1024 + threadIdx.x;
    int v = (i < N) ? deg[i] : 0;
    sh[threadIdx.x] = v;
    __syncthreads();
    for (int off = 1; off < 1024; off <<= 1) {
        int t = (threadIdx.x >= off) ? sh[threadIdx.x - off] : 0;
        __syncthreads();
        sh[threadIdx.x] += t;
        __syncthreads();
    }
    if (i < N) offs[i + 1] = sh[threadIdx.x];
    if (threadIdx.x == 1023) bsum[blockIdx.x] = sh[1023];
    if (i == 0) offs[0] = 0;
}

__global__ __launch_bounds__(1024) void k_scan2(int* __restrict__ bsum, int nb) {
    __shared__ int sh[1024];
    int t = threadIdx.x;
    sh[t] = (t < nb) ? bsum[t] : 0;
    __syncthreads();
    for (int off = 1; off < 1024; off <<= 1) {
        int v = (t >= off) ? sh[t - off] : 0;
        __syncthreads();
        sh[t] += v;
        __syncthreads();
    }
    if (t < nb) bsum[t] = sh[t];
}

__global__ __launch_bounds__(1024) void k_scan3(int* __restrict__ offs,
                                                const int* __restrict__ bsum, int N) {
    int i = blockIdx.x * 1024 + threadIdx.x;
    if (blockIdx.x > 0 && i < N) offs[i + 1] += bsum[blockIdx.x - 1];
}

// ---------------- FUSED layer-0 + layer-1, 16 rows/block, two tiles ----------------
__global__ __launch_bounds__(256) void k_gfused_l01(const unsigned int* __restrict__ fa,
                                                    const unsigned int* __restrict__ fb,
                                                    const int* __restrict__ offs,
                                                    const int* __restrict__ csr,
                                                    const unsigned short* __restrict__ WT0,
                                                    const unsigned short* __restrict__ WT1,
                                                    const unsigned short* __restrict__ WT12,
                                                    const unsigned short* __restrict__ WT13,
                                                    const float* __restrict__ bias,
                                                    unsigned short* __restrict__ t2out,
                                                    unsigned short* __restrict__ t3out,
                                                    int nrows) {
    __shared__ unsigned short tA[16 * TP];   // 4.35KB
    __shared__ unsigned short tB[16 * TP];
    const int t = threadIdx.x;
    const int row0 = blockIdx.x * 16;
    const int l = t & 63, wid = t >> 6;
    const int colw = wid * 32;             // this wave's 32 output cols
    const int rl = l & 15, kq = l >> 4, kl = kq * 8;
    const int q = t & 15, gslot = t >> 4;  // gather: row gslot (0..15), channel chunk q

    // ---- gather a-rows -> tA, b-rows -> tB, back to back (no barrier between) ----
    #pragma unroll
    for (int h = 0; h < 2; ++h) {
        const unsigned int* tbl = h ? fb : fa;
        unsigned short* tile = h ? tB : tA;
        const int row = row0 + gslot;
        float a0=0,a1=0,a2=0,a3=0,a4=0,a5=0,a6=0,a7=0;
        int deg = 0;
        if (row < nrows) {
            int node = (h ? ND : 0) + row;
            int s0 = offs[node];
            deg = offs[node + 1] - s0;
            gather_row(tbl, csr, s0, deg, q, a0,a1,a2,a3,a4,a5,a6,a7);
        }
        float sc = 1.0f / fmaxf((float)deg, 1.0f);
        uint4 o;
        o.x = (unsigned)f2bf(a0*sc) | ((unsigned)f2bf(a1*sc) << 16);
        o.y = (unsigned)f2bf(a2*sc) | ((unsigned)f2bf(a3*sc) << 16);
        o.z = (unsigned)f2bf(a4*sc) | ((unsigned)f2bf(a5*sc) << 16);
        o.w = (unsigned)f2bf(a6*sc) | ((unsigned)f2bf(a7*sc) << 16);
        *(uint4*)(tile + gslot*TP + q*8) = o;
    }
    __syncthreads();

    // ---- MFMA: acc[cf] += tA@WT0 + tB@WT1 (K=256 total), wave owns 32 cols ----
    f32x4 acc[2];
    acc[0] = (f32x4)0.f; acc[1] = (f32x4)0.f;
    #pragma unroll
    for (int h = 0; h < 2; ++h) {
        const unsigned short* tile = h ? tB : tA;
        const unsigned short* WT = h ? WT1 : WT0;
        #pragma unroll
        for (int s = 0; s < 4; ++s) {
            const int k0 = s * 32;
            short8v a = *(const short8v*)(tile + rl*TP + k0 + kl);
            #pragma unroll
            for (int cf = 0; cf < 2; ++cf) {
                short8v b = *(const short8v*)(WT + (size_t)(colw + cf*16 + rl)*HDIM + k0 + kl);
                acc[cf] = __builtin_amdgcn_mfma_f32_16x16x32_bf16(a, b, acc[cf], 0, 0, 0);
            }
        }
    }
    __syncthreads();   // all MFMA reads of tA done before h0 overwrite

    // ---- h0 = relu(acc + bias) -> tA (bf16); D row = kq*4+j (0..15), col = colw+cf*16+rl ----
    #pragma unroll
    for (int cf = 0; cf < 2; ++cf) {
        const float bc = bias[colw + cf*16 + rl];
        #pragma unroll
        for (int j = 0; j < 4; ++j)
            tA[(kq*4 + j)*TP + colw + cf*16 + rl] = f2bf(fmaxf(acc[cf][j] + bc, 0.f));
    }
    __syncthreads();

    // ---- layer-1 transforms: t2 = h0@WT12, t3 = h0@WT13 ----
    #pragma unroll
    for (int h2 = 0; h2 < 2; ++h2) {
        const unsigned short* WT = h2 ? WT13 : WT12;
        unsigned short* outp = h2 ? t3out : t2out;
        f32x4 a2[2];
        a2[0] = (f32x4)0.f; a2[1] = (f32x4)0.f;
        #pragma unroll
        for (int s = 0; s < 4; ++s) {
            const int k0 = s * 32;
            short8v a = *(const short8v*)(tA + rl*TP + k0 + kl);
            #pragma unroll
            for (int cf = 0; cf < 2; ++cf) {
                short8v b = *(const short8v*)(WT + (size_t)(colw + cf*16 + rl)*HDIM + k0 + kl);
                a2[cf] = __builtin_amdgcn_mfma_f32_16x16x32_bf16(a, b, a2[cf], 0, 0, 0);
            }
        }
        #pragma unroll
        for (int cf = 0; cf < 2; ++cf)
            #pragma unroll
            for (int j = 0; j < 4; ++j) {
                int row = row0 + kq*4 + j;
                if (row < nrows)
                    outp[(size_t)row*HDIM + colw + cf*16 + rl] = f2bf(a2[cf][j]);
            }
    }
}

// ---------------- merged fused gather + bias/relu + 128->16 transform (a and b) ----------------
// NA%16==0 so each 16-row block is purely a-side or purely b-side: stage one W, transposed.
__global__ __launch_bounds__(256) void k_gather_trans16_ab(const unsigned int* __restrict__ t2,
                                                           const unsigned int* __restrict__ t3,
                                                           const int* __restrict__ offs,   // offs_all
                                                           const int* __restrict__ csr,
                                                           const float* __restrict__ bias,
                                                           const float* __restrict__ W20,
                                                           const float* __restrict__ W21,
                                                           float* __restrict__ t1a,
                                                           float* __restrict__ t1b) {
    __shared__ float WlT[16 * 132];       // WlT[j][c] = W[c][j]
    __shared__ float vbuf[16 * 132];
    const int t = threadIdx.x;
    const bool blkA = (blockIdx.x < NA/16);
    const float* W = blkA ? W20 : W21;
    {
        const int jj = t & 15, c0 = (t >> 4) * 8;
        #pragma unroll
        for (int i = 0; i < 8; ++i)
            WlT[jj*132 + c0 + i] = W[(size_t)(c0 + i)*DOUT + jj];
    }
    __syncthreads();
    const int w = t >> 6, l = t & 63;
    const int sub = l >> 4, q = l & 15;
    const int lrow = w * 4 + sub;
    const int node = 2*ND + blockIdx.x * 16 + lrow;    // grid exact: < NODE_TOT
    const unsigned int* tbl = blkA ? t2 : t3;
    const int s0 = offs[node];
    const int deg = offs[node + 1] - s0;
    float a0=0,a1=0,a2=0,a3=0,a4=0,a5=0,a6=0,a7=0;
    gather_row(tbl, csr, s0, deg, q, a0,a1,a2,a3,a4,a5,a6,a7);
    const float sc = 1.0f / fmaxf((float)deg, 1.0f);
    const float4 bi0 = *(const float4*)(bias + q*8);
    const float4 bi1 = *(const float4*)(bias + q*8 + 4);
    float4 v0, v1;
    v0.x = fmaxf(a0*sc + bi0.x, 0.f); v0.y = fmaxf(a1*sc + bi0.y, 0.f);
    v0.z = fmaxf(a2*sc + bi0.z, 0.f); v0.w = fmaxf(a3*sc + bi0.w, 0.f);
    v1.x = fmaxf(a4*sc + bi1.x, 0.f); v1.y = fmaxf(a5*sc + bi1.y, 0.f);
    v1.z = fmaxf(a6*sc + bi1.z, 0.f); v1.w = fmaxf(a7*sc + bi1.w, 0.f);
    *(float4*)(vbuf + lrow*132 + q*8)     = v0;
    *(float4*)(vbuf + lrow*132 + q*8 + 4) = v1;
    __syncthreads();
    const int rr = t >> 4, jj = t & 15;
    const float* vr = vbuf + rr*132;
    const float* wr = WlT + jj*132;
    float4 acc4 = make_float4(0.f, 0.f, 0.f, 0.f);
    #pragma unroll 8
    for (int c4 = 0; c4 < 32; ++c4) {
        const float4 v = *(const float4*)(vr + c4*4);
        const float4 ww = *(const float4*)(wr + c4*4);
        acc4.x += v.x*ww.x; acc4.y += v.y*ww.y; acc4.z += v.z*ww.z; acc4.w += v.w*ww.w;
    }
    float acc = (acc4.x + acc4.y) + (acc4.z + acc4.w);
    const int grow = blockIdx.x * 16 + rr;
    if (blkA) t1a[(size_t)grow*DOUT + jj] = acc;
    else      t1b[(size_t)(grow - NA)*DOUT + jj] = acc;
}

// final: out[d] = mean-gather(t0 via rel0) + mean-gather(t1 via rel1) + bias
__global__ __launch_bounds__(256) void k_gather16_combine(const float* __restrict__ t0,
                                                          const float* __restrict__ t1,
                                                          const int* __restrict__ offs0,
                                                          const int* __restrict__ offs1,
                                                          const int* __restrict__ csr,
                                                          const float* __restrict__ bias,
                                                          float* __restrict__ out, int nrows) {
    int t = threadIdx.x;
    int row = blockIdx.x * 64 + (t >> 2);
    if (row >= nrows) return;
    int q = t & 3;
    int c = q * 4;
    float4 acc = make_float4(0.f, 0.f, 0.f, 0.f);
    {
        int s0 = offs0[row], deg = offs0[row + 1] - s0;
        for (int j = 0; j < deg; j += 4) {
            int cnt = deg - j; if (cnt > 4) cnt = 4;
            int myidx = (j + q < deg) ? csr[s0 + j + q] : 0;
            float4 v[4];
            #pragma unroll
            for (int k = 0; k < 4; ++k)
                v[k] = *reinterpret_cast<const float4*>(t0 + (size_t)__shfl(myidx, k, 4)*DOUT + c);
            __builtin_amdgcn_sched_group_barrier(0x020, 4, 0);
            #pragma unroll
            for (int k = 0; k < 4; ++k)
                if (k < cnt) { acc.x += v[k].x; acc.y += v[k].y; acc.z += v[k].z; acc.w += v[k].w; }
        }
        float sc = 1.0f / fmaxf((float)deg, 1.0f);
        acc.x *= sc; acc.y *= sc; acc.z *= sc; acc.w *= sc;
    }
    float4 acc2 = make_float4(0.f, 0.f, 0.f, 0.f);
    {
        int u0 = offs1[row], deg = offs1[row + 1] - u0;
        for (int j = 0; j < deg; j += 4) {
            int cnt = deg - j; if (cnt > 4) cnt = 4;
            int myidx = (j + q < deg) ? csr[u0 + j + q] : 0;
            float4 v[4];
            #pragma unroll
            for (int k = 0; k < 4; ++k)
                v[k] = *reinterpret_cast<const float4*>(t1 + (size_t)__shfl(myidx, k, 4)*DOUT + c);
            __builtin_amdgcn_sched_group_barrier(0x020, 4, 0);
            #pragma unroll
            for (int k = 0; k < 4; ++k)
                if (k < cnt) { acc2.x += v[k].x; acc2.y += v[k].y; acc2.z += v[k].z; acc2.w += v[k].w; }
        }
        float sc2 = 1.0f / fmaxf((float)deg, 1.0f);
        acc2.x *= sc2; acc2.y *= sc2; acc2.z *= sc2; acc2.w *= sc2;
    }
    float4 bi = *reinterpret_cast<const float4*>(bias + c);
    acc.x += acc2.x + bi.x; acc.y += acc2.y + bi.y;
    acc.z += acc2.z + bi.z; acc.w += acc2.w + bi.w;
    *reinterpret_cast<float4*>(out + (size_t)row*DOUT + c) = acc;
}

extern "C" void kernel_launch(void* const* d_in, const int* in_sizes, int n_in,
                              void* d_out, int out_size, void* d_ws, size_t ws_size,
                              hipStream_t stream) {
    const float* feat_a = (const float*)d_in[0];
    const float* feat_b = (const float*)d_in[1];
    const float* basis0 = (const float*)d_in[3];
    const float* coef0  = (const float*)d_in[4];
    const float* bias0  = (const float*)d_in[5];
    const float* basis1 = (const float*)d_in[6];
    const float* coef1  = (const float*)d_in[7];
    const float* bias1  = (const float*)d_in[8];
    const float* basis2 = (const float*)d_in[9];
    const float* coef2  = (const float*)d_in[10];
    const float* bias2  = (const float*)d_in[11];
    const int* s0 = (const int*)d_in[12]; const int* d0 = (const int*)d_in[13];
    const int* s1 = (const int*)d_in[14]; const int* d1 = (const int*)d_in[15];
    const int* s2 = (const int*)d_in[16]; const int* d2 = (const int*)d_in[17];
    const int* s3 = (const int*)d_in[18]; const int* d3 = (const int*)d_in[19];
    const int E0 = in_sizes[12], E1 = in_sizes[14], E2 = in_sizes[16], E3 = in_sizes[18];
    const int Etot = E0 + E1 + E2 + E3;

    // ---- workspace carve-up ----
    char* base = (char*)d_ws;
    auto alloc = [&](size_t bytes) { char* p = base; base += (bytes + 255) & ~(size_t)255; return p; };
    unsigned short* WT00 = (unsigned short*)alloc(HDIM*HDIM*2);
    unsigned short* WT01 = (unsigned short*)alloc(HDIM*HDIM*2);
    unsigned short* WT12 = (unsigned short*)alloc(HDIM*HDIM*2);
    unsigned short* WT13 = (unsigned short*)alloc(HDIM*HDIM*2);
    float* W20 = (float*)alloc(HDIM*DOUT*4);
    float* W21 = (float*)alloc(HDIM*DOUT*4);
    int* offs_all = (int*)alloc((NODE_TOT + 1) * 4);
    int* csr_all  = (int*)alloc((size_t)Etot * 4);
    int* bsum     = (int*)alloc(2048 * 4);
    int* deg      = (int*)alloc(NODE_TOT * 4);
    int* gcur     = (int*)alloc(NBUCKET * 4);
    unsigned int* pairs = (unsigned int*)alloc((size_t)NBUCKET * BCAP * 4);  // 19.2MB fixed regions
    unsigned int* fa_bf  = (unsigned int*)alloc((size_t)NA*HDIM*2);
    unsigned int* fb_bf  = (unsigned int*)alloc((size_t)NB*HDIM*2);
    unsigned int* t2_bf  = (unsigned int*)alloc((size_t)ND*HDIM*2);
    unsigned int* t3_bf  = (unsigned int*)alloc((size_t)ND*HDIM*2);
    float* t1a  = (float*)alloc((size_t)NA*DOUT*4);
    float* t1b  = (float*)alloc((size_t)NB*DOUT*4);
    float* out = (float*)d_out;

    const int* offsR[2] = {offs_all, offs_all + ND};
    const int nbE = (Etot + EPB - 1) / EPB;

    // ---- 1. relation weights + feat bf16 conversion ----
    k_weights_bfT<<<(HDIM*HDIM+255)/256, 256, 0, stream>>>(basis0, coef0, WT00, WT01, 0, 1);
    k_weights_bfT<<<(HDIM*HDIM+255)/256, 256, 0, stream>>>(basis1, coef1, WT12, WT13, 2, 3);
    k_weights<<<(HDIM*DOUT+255)/256, 256, 0, stream>>>(basis2, coef2, W20, W21, 0, 1, HDIM*DOUT);
    k_cvt_bf16_ab<<<((NA+NB)*16)/256, 256, 0, stream>>>(feat_a, feat_b, fa_bf, fb_bf);

    // ---- 2. bucketed CSR build (fixed-capacity buckets) ----
    {
        k_ginit<<<(NBUCKET+255)/256, 256, 0, stream>>>(gcur);
        k_bscatter<<<nbE, 256, 0, stream>>>(s0,d0,s1,d1,s2,d2,s3,d3, E0,E1,E2, Etot, gcur, pairs);
        k_bdeg<<<NBUCKET, 256, 0, stream>>>(pairs, gcur, deg);
        int nb = (NODE_TOT + 1023) / 1024;
        k_scan1<<<nb, 1024, 0, stream>>>(deg, offs_all, bsum, NODE_TOT);
        k_scan2<<<1, 1024, 0, stream>>>(bsum, nb);
        k_scan3<<<nb, 1024, 0, stream>>>(offs_all, bsum, NODE_TOT);
        k_bfill<<<NBUCKET, 256, 0, stream>>>(pairs, gcur, offs_all, csr_all);
    }

    // ---- 3. fused layers 0+1: gather a+b -> MFMA -> h0 (LDS-only) -> t2,t3 (bf16) ----
    k_gfused_l01<<<(ND+15)/16, 256, 0, stream>>>(fa_bf, fb_bf, offs_all, csr_all,
                                                 WT00, WT01, WT12, WT13, bias0,
                                                 (unsigned short*)t2_bf, (unsigned short*)t3_bf, ND);

    // ---- 4. fused layer-1 aggregate + bias/relu + layer-2 transform ----
    k_gather_trans16_ab<<<(NA+NB)/16, 256, 0, stream>>>(t2_bf, t3_bf, offs_all, csr_all,
                                                        bias1, W20, W21, t1a, t1b);

    // ---- 5. final combine ----
    k_gather16_combine<<<(ND+63)/64, 256, 0, stream>>>(t1a, t1b, offsR[0], offsR[1], csr_all,
                                                       bias2, out, ND);
}

// Round 21
// 229.294 us; speedup vs baseline: 1.1503x; 1.0518x over previous
//
#include <hip/hip_runtime.h>

#define NA 100000
#define NB 100000
#define ND 50000
#define HDIM 128
#define DOUT 16
// concatenated dst-node space: rel0 d:[0,ND) rel1 d:[ND,2ND) rel2 a:[2ND,2ND+NA) rel3 b:[2ND+NA,...)
#define NODE_TOT (2*ND + NA + NB)
#define BSH 9
#define BKN 512
#define NBUCKET ((NODE_TOT + BKN - 1) >> BSH)   // 684
#define BCAP 8192                                // fixed pairs capacity per bucket (d-bucket avg 6144)
#define EPB 4096                                 // edges per block, bucket passes
#define TP 136                                   // LDS tile pitch in shorts (272B, 16B-aligned)

typedef __attribute__((ext_vector_type(8))) short short8v;   // 8 bf16 (4 VGPRs)
typedef __attribute__((ext_vector_type(4))) float f32x4;

__device__ __forceinline__ unsigned short f2bf(float f) {
    unsigned u = __float_as_uint(f);
    return (unsigned short)((u + 0x7fffu + ((u >> 16) & 1u)) >> 16);
}
__device__ __forceinline__ void addbf2(float& x, float& y, unsigned u) {
    x += __uint_as_float(u << 16);
    y += __uint_as_float(u & 0xffff0000u);
}

// gather one 128-ch bf16 row-mean: 16 lanes (q = lane&15). Unconditional loads
// (OOB lanes carry myidx=0 -> safe row-0 read), predicated accumulates. Effective
// random-line fetch ~3.6 TB/s — near the L3/HBM random-access ceiling; further
// MLP forcing is bounded by the VGPR file (round 19/20 nulls).
__device__ __forceinline__ void gather_row(const unsigned int* __restrict__ tbl,
                                           const int* __restrict__ csr,
                                           int s0, int deg, int q,
                                           float& a0, float& a1, float& a2, float& a3,
                                           float& a4, float& a5, float& a6, float& a7) {
    int myidx = (q < deg) ? csr[s0 + q] : 0;
    for (int j = 0; j < deg; j += 16) {
        int cnt = deg - j; if (cnt > 16) cnt = 16;
        uint4 v[8];
        #pragma unroll
        for (int k = 0; k < 8; ++k)
            v[k] = *(const uint4*)(tbl + (size_t)__shfl(myidx, k, 16)*64 + q*4);
        #pragma unroll
        for (int k = 0; k < 8; ++k)
            if (k < cnt) { addbf2(a0,a1,v[k].x); addbf2(a2,a3,v[k].y);
                           addbf2(a4,a5,v[k].z); addbf2(a6,a7,v[k].w); }
        if (cnt > 8) {
            #pragma unroll
            for (int k = 8; k < 16; ++k)
                v[k-8] = *(const uint4*)(tbl + (size_t)__shfl(myidx, k, 16)*64 + q*4);
            #pragma unroll
            for (int k = 8; k < 16; ++k)
                if (k < cnt) { addbf2(a0,a1,v[k-8].x); addbf2(a2,a3,v[k-8].y);
                               addbf2(a4,a5,v[k-8].z); addbf2(a6,a7,v[k-8].w); }
        }
        myidx = (j + 16 + q < deg) ? csr[s0 + j + 16 + q] : 0;   // prefetch next batch
    }
}

struct EdgeT { int node; int src; };
__device__ __forceinline__ EdgeT edge_at(int g,
    const int* __restrict__ s0, const int* __restrict__ d0,
    const int* __restrict__ s1, const int* __restrict__ d1,
    const int* __restrict__ s2, const int* __restrict__ d2,
    const int* __restrict__ s3, const int* __restrict__ d3,
    int E0, int E1, int E2) {
    EdgeT e;
    if (g < E0)             { e.node = d0[g];                    e.src = s0[g]; }
    else if (g < E0+E1)     { e.node = ND + d1[g-E0];            e.src = s1[g-E0]; }
    else if (g < E0+E1+E2)  { e.node = 2*ND + d2[g-E0-E1];       e.src = s2[g-E0-E1]; }
    else                    { e.node = 2*ND+NA + d3[g-E0-E1-E2]; e.src = s3[g-E0-E1-E2]; }
    return e;
}

// ---------------- weights (f32, for the 128->16 path) ----------------
__global__ __launch_bounds__(256) void k_weights(const float* __restrict__ basis,
                                                 const float* __restrict__ coef,
                                                 float* __restrict__ W0, float* __restrict__ W1,
                                                 int r0, int r1, int n) {
    int i = blockIdx.x * 256 + threadIdx.x;
    if (i >= n) return;
    float b0 = basis[i], b1 = basis[n + i];
    W0[i] = coef[r0*2+0]*b0 + coef[r0*2+1]*b1;
    W1[i] = coef[r1*2+0]*b0 + coef[r1*2+1]*b1;
}

// bf16 TRANSPOSED weights for MFMA B-operand: WT[n][k] = W[k][n], 128x128
__global__ __launch_bounds__(256) void k_weights_bfT(const float* __restrict__ basis,
                                                     const float* __restrict__ coef,
                                                     unsigned short* __restrict__ WT0,
                                                     unsigned short* __restrict__ WT1,
                                                     int r0, int r1) {
    int i = blockIdx.x * 256 + threadIdx.x;   // i = k*128 + j
    if (i >= HDIM*HDIM) return;
    int k = i >> 7, j = i & 127;
    float b0 = basis[i], b1 = basis[HDIM*HDIM + i];
    WT0[(size_t)j*HDIM + k] = f2bf(coef[r0*2+0]*b0 + coef[r0*2+1]*b1);
    WT1[(size_t)j*HDIM + k] = f2bf(coef[r1*2+0]*b0 + coef[r1*2+1]*b1);
}

// ---------------- fp32 -> bf16 conversion, a and b merged ----------------
__global__ __launch_bounds__(256) void k_cvt_bf16_ab(const float* __restrict__ ina,
                                                     const float* __restrict__ inb,
                                                     unsigned int* __restrict__ outa,
                                                     unsigned int* __restrict__ outb) {
    int i = blockIdx.x * 256 + threadIdx.x;    // grid exact: (NA+NB)*16
    const float* in; unsigned int* out;
    if (i < NA*16) { in = ina; out = outa; }
    else           { in = inb; out = outb; i -= NA*16; }
    const float4 a = *(const float4*)(in + (size_t)i*8);
    const float4 b = *(const float4*)(in + (size_t)i*8 + 4);
    uint4 p;
    p.x = (unsigned)f2bf(a.x) | ((unsigned)f2bf(a.y) << 16);
    p.y = (unsigned)f2bf(a.z) | ((unsigned)f2bf(a.w) << 16);
    p.z = (unsigned)f2bf(b.x) | ((unsigned)f2bf(b.y) << 16);
    p.w = (unsigned)f2bf(b.z) | ((unsigned)f2bf(b.w) << 16);
    *(uint4*)(out + (size_t)i*4) = p;
}

// ---------------- bucketed CSR build (fixed-capacity buckets) ----------------
__global__ __launch_bounds__(256) void k_ginit(int* __restrict__ gcur) {
    int i = blockIdx.x * 256 + threadIdx.x;
    if (i < NBUCKET) gcur[i] = i * BCAP;
}

__global__ __launch_bounds__(256) void k_bscatter(const int* __restrict__ s0, const int* __restrict__ d0,
                                                  const int* __restrict__ s1, const int* __restrict__ d1,
                                                  const int* __restrict__ s2, const int* __restrict__ d2,
                                                  const int* __restrict__ s3, const int* __restrict__ d3,
                                                  int E0, int E1, int E2, int Etot,
                                                  int* __restrict__ gcur,
                                                  unsigned int* __restrict__ pairs) {
    __shared__ int hist[NBUCKET];
    __shared__ int base[NBUCKET];
    for (int i = threadIdx.x; i < NBUCKET; i += 256) hist[i] = 0;
    __syncthreads();
    int g0 = blockIdx.x * EPB + threadIdx.x;
    int nd[EPB/256], sr[EPB/256], rk[EPB/256];
    #pragma unroll
    for (int i = 0; i < EPB/256; ++i) {
        int g = g0 + i*256;
        if (g < Etot) {
            EdgeT e = edge_at(g, s0,d0,s1,d1,s2,d2,s3,d3, E0,E1,E2);
            nd[i] = e.node; sr[i] = e.src;
            rk[i] = atomicAdd(&hist[e.node >> BSH], 1);
        } else nd[i] = -1;
    }
    __syncthreads();
    for (int i = threadIdx.x; i < NBUCKET; i += 256)
        if (hist[i]) base[i] = atomicAdd(&gcur[i], hist[i]);
    __syncthreads();
    #pragma unroll
    for (int i = 0; i < EPB/256; ++i) {
        if (nd[i] >= 0) {
            unsigned p = ((unsigned)(nd[i] & (BKN-1)) << 17) | (unsigned)sr[i];
            pairs[base[nd[i] >> BSH] + rk[i]] = p;
        }
    }
}

// single block: scan bucket counts -> cbase[b] (csr/offs base per bucket)
__global__ __launch_bounds__(1024) void k_bucket_scan(const int* __restrict__ gcur,
                                                      int* __restrict__ cbase) {
    __shared__ int sh[1024];
    int t = threadIdx.x;
    int cntv = (t < NBUCKET) ? (gcur[t] - t * BCAP) : 0;
    sh[t] = cntv;
    __syncthreads();
    for (int off = 1; off < 1024; off <<= 1) {
        int v = (t >= off) ? sh[t - off] : 0;
        __syncthreads();
        sh[t] += v;
        __syncthreads();
    }
    if (t < NBUCKET) cbase[t] = sh[t] - cntv;   // exclusive
}

// one block per bucket: pairs->LDS (once), deg via LDS atomics, 512-scan -> offs,
// csr fill from LDS with LDS cursors. Replaces bdeg + scan1/2/3 + bfill.
__global__ __launch_bounds__(256) void k_bfinal(const unsigned int* __restrict__ pairs,
                                                const int* __restrict__ gcur,
                                                const int* __restrict__ cbase,
                                                int* __restrict__ offs,
                                                int* __restrict__ csr, int Etot) {
    __shared__ unsigned lp[BCAP];   // 32KB
    __shared__ int ldeg[BKN];       // 2KB
    __shared__ int lcur[BKN];       // 2KB
    __shared__ int part[256];       // 1KB
    const int t = threadIdx.x;
    const int b = blockIdx.x;
    const int cnt = gcur[b] - b * BCAP;
    const int cb = cbase[b];
    for (int i = t; i < cnt; i += 256) lp[i] = pairs[(size_t)b * BCAP + i];
    for (int i = t; i < BKN; i += 256) ldeg[i] = 0;
    __syncthreads();
    for (int i = t; i < cnt; i += 256) atomicAdd(&ldeg[lp[i] >> 17], 1);
    __syncthreads();
    // 512-wide exclusive scan: 2 elems/thread + 256-wide Hillis-Steele on partials
    const int d0 = ldeg[2*t], d1 = ldeg[2*t + 1];
    part[t] = d0 + d1;
    __syncthreads();
    for (int off = 1; off < 256; off <<= 1) {
        int v = (t >= off) ? part[t - off] : 0;
        __syncthreads();
        part[t] += v;
        __syncthreads();
    }
    const int excl = t ? part[t - 1] : 0;
    const int nbase = b << BSH;
    const int n0 = nbase + 2*t, n1 = n0 + 1;
    if (n0 < NODE_TOT) { offs[n0] = cb + excl;      lcur[2*t]     = cb + excl; }
    if (n1 < NODE_TOT) { offs[n1] = cb + excl + d0; lcur[2*t + 1] = cb + excl + d0; }
    if (b == NBUCKET - 1 && t == 0) offs[NODE_TOT] = Etot;
    __syncthreads();
    for (int i = t; i < cnt; i += 256) {
        unsigned e = lp[i];
        int p = atomicAdd(&lcur[e >> 17], 1);
        csr[p] = (int)(e & 0x1FFFFu);
    }
}

// ---------------- FUSED layer-0 + layer-1, 16 rows/block, two tiles ----------------
__global__ __launch_bounds__(256) void k_gfused_l01(const unsigned int* __restrict__ fa,
                                                    const unsigned int* __restrict__ fb,
                                                    const int* __restrict__ offs,
                                                    const int* __restrict__ csr,
                                                    const unsigned short* __restrict__ WT0,
                                                    const unsigned short* __restrict__ WT1,
                                                    const unsigned short* __restrict__ WT12,
                                                    const unsigned short* __restrict__ WT13,
                                                    const float* __restrict__ bias,
                                                    unsigned short* __restrict__ t2out,
                                                    unsigned short* __restrict__ t3out,
                                                    int nrows) {
    __shared__ unsigned short tA[16 * TP];   // 4.35KB
    __shared__ unsigned short tB[16 * TP];
    const int t = threadIdx.x;
    const int row0 = blockIdx.x * 16;
    const int l = t & 63, wid = t >> 6;
    const int colw = wid * 32;             // this wave's 32 output cols
    const int rl = l & 15, kq = l >> 4, kl = kq * 8;
    const int q = t & 15, gslot = t >> 4;  // gather: row gslot (0..15), channel chunk q

    // ---- gather a-rows -> tA, b-rows -> tB, back to back (no barrier between) ----
    #pragma unroll
    for (int h = 0; h < 2; ++h) {
        const unsigned int* tbl = h ? fb : fa;
        unsigned short* tile = h ? tB : tA;
        const int row = row0 + gslot;
        float a0=0,a1=0,a2=0,a3=0,a4=0,a5=0,a6=0,a7=0;
        int deg = 0;
        if (row < nrows) {
            int node = (h ? ND : 0) + row;
            int s0 = offs[node];
            deg = offs[node + 1] - s0;
            gather_row(tbl, csr, s0, deg, q, a0,a1,a2,a3,a4,a5,a6,a7);
        }
        float sc = 1.0f / fmaxf((float)deg, 1.0f);
        uint4 o;
        o.x = (unsigned)f2bf(a0*sc) | ((unsigned)f2bf(a1*sc) << 16);
        o.y = (unsigned)f2bf(a2*sc) | ((unsigned)f2bf(a3*sc) << 16);
        o.z = (unsigned)f2bf(a4*sc) | ((unsigned)f2bf(a5*sc) << 16);
        o.w = (unsigned)f2bf(a6*sc) | ((unsigned)f2bf(a7*sc) << 16);
        *(uint4*)(tile + gslot*TP + q*8) = o;
    }
    __syncthreads();

    // ---- MFMA: acc[cf] += tA@WT0 + tB@WT1 (K=256 total), wave owns 32 cols ----
    f32x4 acc[2];
    acc[0] = (f32x4)0.f; acc[1] = (f32x4)0.f;
    #pragma unroll
    for (int h = 0; h < 2; ++h) {
        const unsigned short* tile = h ? tB : tA;
        const unsigned short* WT = h ? WT1 : WT0;
        #pragma unroll
        for (int s = 0; s < 4; ++s) {
            const int k0 = s * 32;
            short8v a = *(const short8v*)(tile + rl*TP + k0 + kl);
            #pragma unroll
            for (int cf = 0; cf < 2; ++cf) {
                short8v b = *(const short8v*)(WT + (size_t)(colw + cf*16 + rl)*HDIM + k0 + kl);
                acc[cf] = __builtin_amdgcn_mfma_f32_16x16x32_bf16(a, b, acc[cf], 0, 0, 0);
            }
        }
    }
    __syncthreads();   // all MFMA reads of tA done before h0 overwrite

    // ---- h0 = relu(acc + bias) -> tA (bf16); D row = kq*4+j (0..15), col = colw+cf*16+rl ----
    #pragma unroll
    for (int cf = 0; cf < 2; ++cf) {
        const float bc = bias[colw + cf*16 + rl];
        #pragma unroll
        for (int j = 0; j < 4; ++j)
            tA[(kq*4 + j)*TP + colw + cf*16 + rl] = f2bf(fmaxf(acc[cf][j] + bc, 0.f));
    }
    __syncthreads();

    // ---- layer-1 transforms: t2 = h0@WT12, t3 = h0@WT13 ----
    #pragma unroll
    for (int h2 = 0; h2 < 2; ++h2) {
        const unsigned short* WT = h2 ? WT13 : WT12;
        unsigned short* outp = h2 ? t3out : t2out;
        f32x4 a2[2];
        a2[0] = (f32x4)0.f; a2[1] = (f32x4)0.f;
        #pragma unroll
        for (int s = 0; s < 4; ++s) {
            const int k0 = s * 32;
            short8v a = *(const short8v*)(tA + rl*TP + k0 + kl);
            #pragma unroll
            for (int cf = 0; cf < 2; ++cf) {
                short8v b = *(const short8v*)(WT + (size_t)(colw + cf*16 + rl)*HDIM + k0 + kl);
                a2[cf] = __builtin_amdgcn_mfma_f32_16x16x32_bf16(a, b, a2[cf], 0, 0, 0);
            }
        }
        #pragma unroll
        for (int cf = 0; cf < 2; ++cf)
            #pragma unroll
            for (int j = 0; j < 4; ++j) {
                int row = row0 + kq*4 + j;
                if (row < nrows)
                    outp[(size_t)row*HDIM + colw + cf*16 + rl] = f2bf(a2[cf][j]);
            }
    }
}

// ---------------- merged fused gather + bias/relu + 128->16 transform (a and b) ----------------
// NA%16==0 so each 16-row block is purely a-side or purely b-side: stage one W, transposed.
__global__ __launch_bounds__(256) void k_gather_trans16_ab(const unsigned int* __restrict__ t2,
                                                           const unsigned int* __restrict__ t3,
                                                           const int* __restrict__ offs,   // offs_all
                                                           const int* __restrict__ csr,
                                                           const float* __restrict__ bias,
                                                           const float* __restrict__ W20,
                                                           const float* __restrict__ W21,
                                                           float* __restrict__ t1a,
                                                           float* __restrict__ t1b) {
    __shared__ float WlT[16 * 132];       // WlT[j][c] = W[c][j]
    __shared__ float vbuf[16 * 132];
    const int t = threadIdx.x;
    const bool blkA = (blockIdx.x < NA/16);
    const float* W = blkA ? W20 : W21;
    {
        const int jj = t & 15, c0 = (t >> 4) * 8;
        #pragma unroll
        for (int i = 0; i < 8; ++i)
            WlT[jj*132 + c0 + i] = W[(size_t)(c0 + i)*DOUT + jj];
    }
    __syncthreads();
    const int w = t >> 6, l = t & 63;
    const int sub = l >> 4, q = l & 15;
    const int lrow = w * 4 + sub;
    const int node = 2*ND + blockIdx.x * 16 + lrow;    // grid exact: < NODE_TOT
    const unsigned int* tbl = blkA ? t2 : t3;
    const int s0 = offs[node];
    const int deg = offs[node + 1] - s0;
    float a0=0,a1=0,a2=0,a3=0,a4=0,a5=0,a6=0,a7=0;
    gather_row(tbl, csr, s0, deg, q, a0,a1,a2,a3,a4,a5,a6,a7);
    const float sc = 1.0f / fmaxf((float)deg, 1.0f);
    const float4 bi0 = *(const float4*)(bias + q*8);
    const float4 bi1 = *(const float4*)(bias + q*8 + 4);
    float4 v0, v1;
    v0.x = fmaxf(a0*sc + bi0.x, 0.f); v0.y = fmaxf(a1*sc + bi0.y, 0.f);
    v0.z = fmaxf(a2*sc + bi0.z, 0.f); v0.w = fmaxf(a3*sc + bi0.w, 0.f);
    v1.x = fmaxf(a4*sc + bi1.x, 0.f); v1.y = fmaxf(a5*sc + bi1.y, 0.f);
    v1.z = fmaxf(a6*sc + bi1.z, 0.f); v1.w = fmaxf(a7*sc + bi1.w, 0.f);
    *(float4*)(vbuf + lrow*132 + q*8)     = v0;
    *(float4*)(vbuf + lrow*132 + q*8 + 4) = v1;
    __syncthreads();
    const int rr = t >> 4, jj = t & 15;
    const float* vr = vbuf + rr*132;
    const float* wr = WlT + jj*132;
    float4 acc4 = make_float4(0.f, 0.f, 0.f, 0.f);
    #pragma unroll 8
    for (int c4 = 0; c4 < 32; ++c4) {
        const float4 v = *(const float4*)(vr + c4*4);
        const float4 ww = *(const float4*)(wr + c4*4);
        acc4.x += v.x*ww.x; acc4.y += v.y*ww.y; acc4.z += v.z*ww.z; acc4.w += v.w*ww.w;
    }
    float acc = (acc4.x + acc4.y) + (acc4.z + acc4.w);
    const int grow = blockIdx.x * 16 + rr;
    if (blkA) t1a[(size_t)grow*DOUT + jj] = acc;
    else      t1b[(size_t)(grow - NA)*DOUT + jj] = acc;
}

// final: out[d] = mean-gather(t0 via rel0) + mean-gather(t1 via rel1) + bias
__global__ __launch_bounds__(256) void k_gather16_combine(const float* __restrict__ t0,
                                                          const float* __restrict__ t1,
                                                          const int* __restrict__ offs0,
                                                          const int* __restrict__ offs1,
                                                          const int* __restrict__ csr,
                                                          const float* __restrict__ bias,
                                                          float* __restrict__ out, int nrows) {
    int t = threadIdx.x;
    int row = blockIdx.x * 64 + (t >> 2);
    if (row >= nrows) return;
    int q = t & 3;
    int c = q * 4;
    float4 acc = make_float4(0.f, 0.f, 0.f, 0.f);
    {
        int s0 = offs0[row], deg = offs0[row + 1] - s0;
        for (int j = 0; j < deg; j += 4) {
            int cnt = deg - j; if (cnt > 4) cnt = 4;
            int myidx = (j + q < deg) ? csr[s0 + j + q] : 0;
            float4 v[4];
            #pragma unroll
            for (int k = 0; k < 4; ++k)
                v[k] = *reinterpret_cast<const float4*>(t0 + (size_t)__shfl(myidx, k, 4)*DOUT + c);
            #pragma unroll
            for (int k = 0; k < 4; ++k)
                if (k < cnt) { acc.x += v[k].x; acc.y += v[k].y; acc.z += v[k].z; acc.w += v[k].w; }
        }
        float sc = 1.0f / fmaxf((float)deg, 1.0f);
        acc.x *= sc; acc.y *= sc; acc.z *= sc; acc.w *= sc;
    }
    float4 acc2 = make_float4(0.f, 0.f, 0.f, 0.f);
    {
        int u0 = offs1[row], deg = offs1[row + 1] - u0;
        for (int j = 0; j < deg; j += 4) {
            int cnt = deg - j; if (cnt > 4) cnt = 4;
            int myidx = (j + q < deg) ? csr[u0 + j + q] : 0;
            float4 v[4];
            #pragma unroll
            for (int k = 0; k < 4; ++k)
                v[k] = *reinterpret_cast<const float4*>(t1 + (size_t)__shfl(myidx, k, 4)*DOUT + c);
            #pragma unroll
            for (int k = 0; k < 4; ++k)
                if (k < cnt) { acc2.x += v[k].x; acc2.y += v[k].y; acc2.z += v[k].z; acc2.w += v[k].w; }
        }
        float sc2 = 1.0f / fmaxf((float)deg, 1.0f);
        acc2.x *= sc2; acc2.y *= sc2; acc2.z *= sc2; acc2.w *= sc2;
    }
    float4 bi = *reinterpret_cast<const float4*>(bias + c);
    acc.x += acc2.x + bi.x; acc.y += acc2.y + bi.y;
    acc.z += acc2.z + bi.z; acc.w += acc2.w + bi.w;
    *reinterpret_cast<float4*>(out + (size_t)row*DOUT + c) = acc;
}

extern "C" void kernel_launch(void* const* d_in, const int* in_sizes, int n_in,
                              void* d_out, int out_size, void* d_ws, size_t ws_size,
                              hipStream_t stream) {
    const float* feat_a = (const float*)d_in[0];
    const float* feat_b = (const float*)d_in[1];
    const float* basis0 = (const float*)d_in[3];
    const float* coef0  = (const float*)d_in[4];
    const float* bias0  = (const float*)d_in[5];
    const float* basis1 = (const float*)d_in[6];
    const float* coef1  = (const float*)d_in[7];
    const float* bias1  = (const float*)d_in[8];
    const float* basis2 = (const float*)d_in[9];
    const float* coef2  = (const float*)d_in[10];
    const float* bias2  = (const float*)d_in[11];
    const int* s0 = (const int*)d_in[12]; const int* d0 = (const int*)d_in[13];
    const int* s1 = (const int*)d_in[14]; const int* d1 = (const int*)d_in[15];
    const int* s2 = (const int*)d_in[16]; const int* d2 = (const int*)d_in[17];
    const int* s3 = (const int*)d_in[18]; const int* d3 = (const int*)d_in[19];
    const int E0 = in_sizes[12], E1 = in_sizes[14], E2 = in_sizes[16], E3 = in_sizes[18];
    const int Etot = E0 + E1 + E2 + E3;

    // ---- workspace carve-up ----
    char* base = (char*)d_ws;
    auto alloc = [&](size_t bytes) { char* p = base; base += (bytes + 255) & ~(size_t)255; return p; };
    unsigned short* WT00 = (unsigned short*)alloc(HDIM*HDIM*2);
    unsigned short* WT01 = (unsigned short*)alloc(HDIM*HDIM*2);
    unsigned short* WT12 = (unsigned short*)alloc(HDIM*HDIM*2);
    unsigned short* WT13 = (unsigned short*)alloc(HDIM*HDIM*2);
    float* W20 = (float*)alloc(HDIM*DOUT*4);
    float* W21 = (float*)alloc(HDIM*DOUT*4);
    int* offs_all = (int*)alloc((NODE_TOT + 1) * 4);
    int* csr_all  = (int*)alloc((size_t)Etot * 4);
    int* gcur     = (int*)alloc(NBUCKET * 4);
    int* cbase    = (int*)alloc(NBUCKET * 4);
    unsigned int* pairs = (unsigned int*)alloc((size_t)NBUCKET * BCAP * 4);  // fixed regions
    unsigned int* fa_bf  = (unsigned int*)alloc((size_t)NA*HDIM*2);
    unsigned int* fb_bf  = (unsigned int*)alloc((size_t)NB*HDIM*2);
    unsigned int* t2_bf  = (unsigned int*)alloc((size_t)ND*HDIM*2);
    unsigned int* t3_bf  = (unsigned int*)alloc((size_t)ND*HDIM*2);
    float* t1a  = (float*)alloc((size_t)NA*DOUT*4);
    float* t1b  = (float*)alloc((size_t)NB*DOUT*4);
    float* out = (float*)d_out;

    const int* offsR[2] = {offs_all, offs_all + ND};
    const int nbE = (Etot + EPB - 1) / EPB;

    // ---- 1. relation weights + feat bf16 conversion ----
    k_weights_bfT<<<(HDIM*HDIM+255)/256, 256, 0, stream>>>(basis0, coef0, WT00, WT01, 0, 1);
    k_weights_bfT<<<(HDIM*HDIM+255)/256, 256, 0, stream>>>(basis1, coef1, WT12, WT13, 2, 3);
    k_weights<<<(HDIM*DOUT+255)/256, 256, 0, stream>>>(basis2, coef2, W20, W21, 0, 1, HDIM*DOUT);
    k_cvt_bf16_ab<<<((NA+NB)*16)/256, 256, 0, stream>>>(feat_a, feat_b, fa_bf, fb_bf);

    // ---- 2. bucketed CSR build (consolidated: scatter -> bucket_scan -> bfinal) ----
    {
        k_ginit<<<(NBUCKET+255)/256, 256, 0, stream>>>(gcur);
        k_bscatter<<<nbE, 256, 0, stream>>>(s0,d0,s1,d1,s2,d2,s3,d3, E0,E1,E2, Etot, gcur, pairs);
        k_bucket_scan<<<1, 1024, 0, stream>>>(gcur, cbase);
        k_bfinal<<<NBUCKET, 256, 0, stream>>>(pairs, gcur, cbase, offs_all, csr_all, Etot);
    }

    // ---- 3. fused layers 0+1: gather a+b -> MFMA -> h0 (LDS-only) -> t2,t3 (bf16) ----
    k_gfused_l01<<<(ND+15)/16, 256, 0, stream>>>(fa_bf, fb_bf, offs_all, csr_all,
                                                 WT00, WT01, WT12, WT13, bias0,
                                                 (unsigned short*)t2_bf, (unsigned short*)t3_bf, ND);

    // ---- 4. fused layer-1 aggregate + bias/relu + layer-2 transform ----
    k_gather_trans16_ab<<<(NA+NB)/16, 256, 0, stream>>>(t2_bf, t3_bf, offs_all, csr_all,
                                                        bias1, W20, W21, t1a, t1b);

    // ---- 5. final combine ----
    k_gather16_combine<<<(ND+63)/64, 256, 0, stream>>>(t1a, t1b, offsR[0], offsR[1], csr_all,
                                                       bias2, out, ND);
}